// Round 7
// baseline (163.160 us; speedup 1.0000x reference)
//
#include <hip/hip_runtime.h>

// ---------------------------------------------------------------------------
// B=4, N1=1024, N2=1024, D=256, H=4, Dh=64
//   u[b,i,4] = gelu(prev@W_pre+b_pre) @ W_fuse[0:6]
//   v[b,j,4] = gelu(curr@W_cur+b_cur) @ W_fuse[6:12] + b_fuse
//   c = mask ? u_i+v_j : 0
//   Gd_j[8] = gelu(d_j)@W_ffn[4:8] + gelu(e_j)@W_ffn[8:12] + b_ffn
//   logits = gelu(gelu(c)@W_ffn[0:4] + Gd_j)@W_fcc + b_fcc
//   softmax over i WITHOUT max-subtraction (logits bounded; masked -> exp=0)
//   res = P @ prev (per-head);  g_j = (T_j@W_ffn[0:4]+cnt*Gd_j)/(cnt+1)
//   out = res + gelu(g)@W_fcg + b_fcg
// Round-6 lesson: softmax denominators are PER (column, HEAD) — Sws must be
// 32/block (h*8+jl), written by dq==0 threads; head h must read its own sum.
// Round-5 lesson: acc[8][8]/thread -> VGPR=136 (over 128 cliff, 8 waves/CU).
// Round-4 lesson: never cap __launch_bounds__ min-waves (spill -> HBM).
// ---------------------------------------------------------------------------

__device__ __forceinline__ float gelu_f(float x){
    float x3 = x*x*x;
    float t2 = 1.5957691216057308f * (x + 0.044715f*x3);
    float e  = __expf(t2);
    return x - __fdividef(x, e + 1.0f);
}

// ---- kernel 1: per-row u (prev side) and v (curr side), one wave per row ----
__global__ __launch_bounds__(256) void k_rows(
    const float* __restrict__ prev, const float* __restrict__ curr,
    const float* __restrict__ W_pre, const float* __restrict__ b_pre,
    const float* __restrict__ W_cur, const float* __restrict__ b_cur,
    const float* __restrict__ W_fuse, const float* __restrict__ b_fuse,
    float* __restrict__ u_ws, float* __restrict__ v_ws)
{
    int gid  = blockIdx.x * 256 + threadIdx.x;
    int wave = gid >> 6;
    int lane = threadIdx.x & 63;
    bool isPrev = wave < 4096;
    int row = isPrev ? wave : (wave - 4096);
    const float* xrow = (isPrev ? prev : curr) + (size_t)row * 256;
    const float* W  = isPrev ? W_pre : W_cur;
    const float* bv = isPrev ? b_pre : b_cur;

    float4 x4 = *reinterpret_cast<const float4*>(xrow + lane*4);
    const float* Wl = W + lane*24;
    float p[6];
    #pragma unroll
    for (int k=0;k<6;++k)
        p[k] = x4.x*Wl[k] + x4.y*Wl[6+k] + x4.z*Wl[12+k] + x4.w*Wl[18+k];
    #pragma unroll
    for (int off=32; off>=1; off>>=1){
        #pragma unroll
        for (int k=0;k<6;++k) p[k] += __shfl_xor(p[k], off, 64);
    }
    if (lane == 0){
        float g[6];
        #pragma unroll
        for(int k=0;k<6;++k) g[k] = gelu_f(p[k] + bv[k]);
        int rb = isPrev ? 0 : 6;
        float o[4];
        #pragma unroll
        for(int kk=0;kk<4;++kk){
            float a = isPrev ? 0.0f : b_fuse[kk];
            #pragma unroll
            for(int k=0;k<6;++k) a += g[k]*W_fuse[(rb+k)*4+kk];
            o[kk]=a;
        }
        float* dst = (isPrev ? u_ws : v_ws) + (size_t)row*4;
        *reinterpret_cast<float4*>(dst) = make_float4(o[0],o[1],o[2],o[3]);
    }
}

// ---- kernel 2: per-column reductions over edges + Gd precompute ----
__global__ __launch_bounds__(256) void k_cols(
    const int* __restrict__ edges,
    const float* __restrict__ u_ws, const float* __restrict__ v_ws,
    const float* __restrict__ W_ffn, const float* __restrict__ b_ffn,
    float* __restrict__ Gd_ws, float* __restrict__ cnt_ws)
{
    int b  = blockIdx.x >> 6;
    int j0 = (blockIdx.x & 63) * 16;
    int t  = threadIdx.x;
    int jq = t & 3, sl = t >> 2;
    const int*   eb = edges + (size_t)b*1048576 + j0 + jq*4;
    const float* ub = u_ws + (size_t)b*4096;

    int   cnt[4] = {0,0,0,0};
    float S[4][4] = {{0.f}};
    float M[4][4];
    #pragma unroll
    for (int q=0;q<4;++q)
        #pragma unroll
        for (int k=0;k<4;++k) M[q][k] = -3.4e38f;

    #pragma unroll 4
    for (int ii=0; ii<16; ++ii){
        int i = sl*16 + ii;
        int4   e4 = *reinterpret_cast<const int4*>(eb + (size_t)i*1024);
        float4 u4 = *reinterpret_cast<const float4*>(ub + i*4);
        float uu[4] = {u4.x,u4.y,u4.z,u4.w};
        int   ee[4] = {e4.x,e4.y,e4.z,e4.w};
        #pragma unroll
        for (int q=0;q<4;++q){
            bool mk = ee[q]!=0;
            cnt[q] += mk ? 1 : 0;
            #pragma unroll
            for (int k=0;k<4;++k){
                S[q][k] += mk ? uu[k] : 0.0f;
                M[q][k]  = mk ? fmaxf(M[q][k],uu[k]) : M[q][k];
            }
        }
    }
    __shared__ float rS[64][16][4];
    __shared__ float rM[64][16][4];
    __shared__ int   rC[64][16];
    #pragma unroll
    for (int q=0;q<4;++q){
        int c = jq*4+q;
        #pragma unroll
        for (int k=0;k<4;++k){ rS[sl][c][k]=S[q][k]; rM[sl][c][k]=M[q][k]; }
        rC[sl][c]=cnt[q];
    }
    __syncthreads();
    float aS[4], aM[4]; int aC=0; int c2=0, hf=0;
    if (t < 128){
        c2 = t & 15; hf = t >> 4;
        #pragma unroll
        for(int k=0;k<4;++k){ aS[k]=0.f; aM[k]=-3.4e38f; }
        for (int s2=hf*8; s2<hf*8+8; ++s2){
            aC += rC[s2][c2];
            #pragma unroll
            for(int k=0;k<4;++k){ aS[k]+=rS[s2][c2][k]; aM[k]=fmaxf(aM[k],rM[s2][c2][k]); }
        }
    }
    __syncthreads();
    if (t < 128){
        rC[hf][c2]=aC;
        #pragma unroll
        for(int k=0;k<4;++k){ rS[hf][c2][k]=aS[k]; rM[hf][c2][k]=aM[k]; }
    }
    __syncthreads();
    if (t < 16){
        int cc=0; float Sa[4]={0,0,0,0};
        float Ma[4]={-3.4e38f,-3.4e38f,-3.4e38f,-3.4e38f};
        for (int s2=0;s2<8;++s2){
            cc += rC[s2][t];
            #pragma unroll
            for(int k=0;k<4;++k){ Sa[k]+=rS[s2][t][k]; Ma[k]=fmaxf(Ma[k],rM[s2][t][k]); }
        }
        size_t cj = (size_t)b*1024 + j0 + t;
        float4 v4 = *reinterpret_cast<const float4*>(v_ws + cj*4);
        float vv[4]={v4.x,v4.y,v4.z,v4.w};
        float cf = (float)cc, e1 = cf + 1.0f;
        float gd[4], ge[4];
        #pragma unroll
        for(int k=0;k<4;++k){
            float dk = (Sa[k] + cf*vv[k]) / e1;
            float ek;
            if (cc == 0) ek = 0.0f;
            else { float m1 = Ma[k]+vv[k]; ek = (cc < 1024) ? fmaxf(m1, 0.0f) : m1; }
            gd[k]=gelu_f(dk); ge[k]=gelu_f(ek);
        }
        #pragma unroll
        for(int kk=0;kk<8;++kk){
            float a = b_ffn[kk];
            #pragma unroll
            for(int k=0;k<4;++k)
                a += gd[k]*W_ffn[(4+k)*8+kk] + ge[k]*W_ffn[(8+k)*8+kk];
            Gd_ws[cj*8+kk]=a;
        }
        cnt_ws[cj]=cf;
    }
}

// ---- kernel 3: logits + exp-sum + weighted prev; writes partials ----
// Block = (b, jtile of 8 cols, sp i-part). 256 threads, grid 4*128*SPLIT.
// Logit role: (il_w=t>>3 in 0..31, jl_w=t&7).
// PV role:    (jl=t&7 col, h=(t>>3)&3, dq=t>>5 in 0..7) — each thread owns
//             one column's dims [h*64+dq*8, +8) and loops over ALL 64 rows.
// acc[8]+s per thread; NO intra-block merge. s is per (col, head): Sws gets
// 32 entries/block written by dq==0 threads (t<32, index h*8+jl).
template<int SPLIT>
__global__ __launch_bounds__(256) void k_main(
    const float* __restrict__ prev, const int* __restrict__ edges,
    const float* __restrict__ u_ws, const float* __restrict__ v_ws,
    const float* __restrict__ Gd_ws,
    const float* __restrict__ W_ffn, const float* __restrict__ W_fcc,
    const float* __restrict__ b_fcc,
    float* __restrict__ Pws, float* __restrict__ Sws, float* __restrict__ Tws)
{
    int bid = blockIdx.x;
    int sp  = bid & (SPLIT-1);
    int jt  = (bid / SPLIT) & 127;
    int b   = bid / (SPLIT*128);
    int j0  = jt*8;
    int t   = threadIdx.x;
    int jl_w = t & 7, il_w = t >> 3;
    int jl = t & 7, h = (t >> 3) & 3, dq = t >> 5;

    __shared__ float sLog[64*36];    // [il][h*8+jl], stride 36
    __shared__ float sU[64][4];
    __shared__ float sV[8][4];
    __shared__ float sGd[8][8];

    if (t < 32) (&sV[0][0])[t]  = v_ws[((size_t)b*1024 + j0)*4 + t];
    if (t < 64) (&sGd[0][0])[t] = Gd_ws[((size_t)b*1024 + j0)*8 + t];

    // uniform weights -> scalar regs
    float W4r[4][8], Wfc[8][4], bfc[4];
    #pragma unroll
    for(int k=0;k<4;++k)
        #pragma unroll
        for(int kk=0;kk<8;++kk) W4r[k][kk]=W_ffn[k*8+kk];
    #pragma unroll
    for(int kk=0;kk<8;++kk)
        #pragma unroll
        for(int hh=0;hh<4;++hh) Wfc[kk][hh]=W_fcc[kk*4+hh];
    #pragma unroll
    for(int hh=0;hh<4;++hh) bfc[hh]=b_fcc[hh];

    float s = 0.0f, acc[8] = {0,0,0,0,0,0,0,0};
    float Tp[4] = {0,0,0,0};

    const int*   ebase  = edges + (size_t)b*1048576 + j0;
    const float* pbBase = prev  + (size_t)b*262144 + h*64 + dq*8;

    const int NCH = 16/SPLIT;
    for (int cc=0; cc<NCH; ++cc){
        int i0 = sp*(1024/SPLIT) + cc*64;
        __syncthreads();
        (&sU[0][0])[t] = u_ws[((size_t)b*1024 + i0)*4 + t];
        __syncthreads();

        // ---- logit phase: 512 pairs, 2 per thread ----
        #pragma unroll
        for (int r=0;r<2;++r){
            int il = il_w + 32*r;
            int eg = ebase[(size_t)(i0+il)*1024 + jl_w];
            float gc[4];
            #pragma unroll
            for(int k=0;k<4;++k){
                float ccv = sU[il][k] + sV[jl_w][k];
                gc[k] = gelu_f(ccv);
                Tp[k] += eg ? gc[k] : 0.0f;
            }
            float fu[8];
            #pragma unroll
            for(int kk=0;kk<8;++kk){
                float a = sGd[jl_w][kk];
                #pragma unroll
                for(int k=0;k<4;++k) a += gc[k]*W4r[k][kk];
                fu[kk] = gelu_f(a);
            }
            #pragma unroll
            for(int hh=0;hh<4;++hh){
                float a = bfc[hh];
                #pragma unroll
                for(int kk=0;kk<8;++kk) a += fu[kk]*Wfc[kk][hh];
                sLog[il*36 + hh*8 + jl_w] = eg ? a : -1e30f;
            }
        }
        __syncthreads();

        // ---- PV: all 64 rows, own column jl, head h, dims [h*64+dq*8, +8) ----
        const float* pc = pbBase + (size_t)i0*256;
        const float* lg = sLog + h*8 + jl;
        #pragma unroll 4
        for (int i=0;i<64;++i){
            float w = __expf(lg[i*36]);        // masked -> exp(-1e30) = 0
            float4 a0 = *reinterpret_cast<const float4*>(pc + (size_t)i*256);
            float4 a1 = *reinterpret_cast<const float4*>(pc + (size_t)i*256 + 4);
            s += w;
            acc[0]+=w*a0.x; acc[1]+=w*a0.y; acc[2]+=w*a0.z; acc[3]+=w*a0.w;
            acc[4]+=w*a1.x; acc[5]+=w*a1.y; acc[6]+=w*a1.z; acc[7]+=w*a1.w;
        }
    }

    size_t bp = ((size_t)b*128 + jt)*SPLIT + sp;

    // ---- T reduction (sLog reused as sT[32][8][4]) ----
    __syncthreads();
    float* sT = sLog;
    #pragma unroll
    for (int k=0;k<4;++k) sT[(il_w*8 + jl_w)*4 + k] = Tp[k];
    __syncthreads();
    if (t < 8){
        float T0=0,T1=0,T2=0,T3=0;
        for (int s2=0;s2<32;++s2){
            const float* p = sT + (s2*8+t)*4;
            T0+=p[0];T1+=p[1];T2+=p[2];T3+=p[3];
        }
        float* td = Tws + (bp*8 + t)*4;
        td[0]=T0; td[1]=T1; td[2]=T2; td[3]=T3;
    }
    if (t < 32) Sws[bp*32 + t] = s;   // t = h*8+jl (dq==0): per-(head,col) sum
    float* dst = Pws + ((size_t)bp*256 + t)*8;
    float4* d4 = reinterpret_cast<float4*>(dst);
    d4[0] = make_float4(acc[0],acc[1],acc[2],acc[3]);
    d4[1] = make_float4(acc[4],acc[5],acc[6],acc[7]);
}

// ---- kernel 4: merge split partials, normalize, add gelu(g)@W_fcg ----
// Block = (b, jtile of 8 cols), grid 512. Thread (jl=t&7, h=(t>>3)&3, dq=t>>5)
// mirrors k_main's PV mapping; head h reads its own denominator (t&31).
template<int SPLIT>
__global__ __launch_bounds__(256) void k_merge(
    const float* __restrict__ Pws, const float* __restrict__ Sws,
    const float* __restrict__ Tws,
    const float* __restrict__ Gd_ws, const float* __restrict__ cnt_ws,
    const float* __restrict__ W_ffn, const float* __restrict__ W_fcg,
    const float* __restrict__ b_fcg, float* __restrict__ out)
{
    int b  = blockIdx.x >> 7;
    int jt = blockIdx.x & 127;
    int j0 = jt*8;
    int t  = threadIdx.x;
    int jl = t & 7, h = (t >> 3) & 3, dq = t >> 5;
    int hc = t & 31;                  // h*8 + jl
    __shared__ float sG[8][8];

    size_t bp0 = ((size_t)b*128 + jt)*SPLIT;
    float s = 0.0f, acc[8] = {0,0,0,0,0,0,0,0};
    #pragma unroll
    for (int sp2=0; sp2<SPLIT; ++sp2){
        const float* p = Pws + ((bp0+sp2)*256 + t)*8;
        float4 p0 = *reinterpret_cast<const float4*>(p);
        float4 p1 = *reinterpret_cast<const float4*>(p+4);
        acc[0]+=p0.x; acc[1]+=p0.y; acc[2]+=p0.z; acc[3]+=p0.w;
        acc[4]+=p1.x; acc[5]+=p1.y; acc[6]+=p1.z; acc[7]+=p1.w;
        s += Sws[(bp0+sp2)*32 + hc];
    }
    if (t < 8){
        float T[4] = {0,0,0,0};
        #pragma unroll
        for (int sp2=0; sp2<SPLIT; ++sp2){
            const float* tp = Tws + ((bp0+sp2)*8 + t)*4;
            #pragma unroll
            for (int k=0;k<4;++k) T[k]+=tp[k];
        }
        size_t cj = (size_t)b*1024 + j0 + t;
        float cf = cnt_ws[cj];
        float inv = __fdividef(1.0f, cf + 1.0f);
        #pragma unroll
        for (int kk=0;kk<8;++kk){
            float a = cf*Gd_ws[cj*8+kk];
            #pragma unroll
            for (int k=0;k<4;++k) a += T[k]*W_ffn[k*8+kk];
            sG[t][kk] = gelu_f(a*inv);
        }
    }
    __syncthreads();

    float rs = (s > 0.0f) ? (1.0f/s) : 0.0f;
    int col0 = h*64 + dq*8;
    float gg[8];
    #pragma unroll
    for (int kk=0;kk<8;++kk) gg[kk]=sG[jl][kk];
    float o[8];
    #pragma unroll
    for (int d2=0;d2<8;++d2){
        float a = b_fcg[col0+d2];
        #pragma unroll
        for (int kk=0;kk<8;++kk) a += gg[kk]*W_fcg[kk*256 + col0 + d2];
        o[d2] = acc[d2]*rs + a;
    }
    float* ob = out + ((size_t)b*1024 + j0 + jl)*256 + col0;
    float4* o4 = reinterpret_cast<float4*>(ob);
    o4[0] = make_float4(o[0],o[1],o[2],o[3]);
    o4[1] = make_float4(o[4],o[5],o[6],o[7]);
}

extern "C" void kernel_launch(void* const* d_in, const int* in_sizes, int n_in,
                              void* d_out, int out_size, void* d_ws, size_t ws_size,
                              hipStream_t stream)
{
    const float* prev  = (const float*)d_in[0];
    const float* curr  = (const float*)d_in[1];
    const int*   edges = (const int*)  d_in[2];
    const float* W_pre = (const float*)d_in[3];
    const float* b_pre = (const float*)d_in[4];
    const float* W_cur = (const float*)d_in[5];
    const float* b_cur = (const float*)d_in[6];
    const float* W_fuse= (const float*)d_in[7];
    const float* b_fuse= (const float*)d_in[8];
    const float* W_ffn = (const float*)d_in[9];
    const float* b_ffn = (const float*)d_in[10];
    const float* W_fcc = (const float*)d_in[11];
    const float* b_fcc = (const float*)d_in[12];
    const float* W_fcg = (const float*)d_in[13];
    const float* b_fcg = (const float*)d_in[14];
    float* out = (float*)d_out;

    float* u_ws   = (float*)d_ws;          // 16384 floats
    float* v_ws   = u_ws  + 16384;         // 16384
    float* Gd_ws  = v_ws  + 16384;         // 32768
    float* cnt_ws = Gd_ws + 32768;         // 4096
    float* Pws    = cnt_ws + 4096;
    const size_t base_f = 16384 + 16384 + 32768 + 4096;
    const size_t p2 = (size_t)4*128*2*256*8;            // 2,097,152 floats
    const size_t s2 = (size_t)4*128*2*32;               // 32,768
    const size_t t2 = (size_t)4*128*2*8*4;              // 32,768
    const size_t need2 = (base_f + p2 + s2 + t2) * 4;

    k_rows<<<dim3(2048), dim3(256), 0, stream>>>(prev, curr, W_pre, b_pre,
        W_cur, b_cur, W_fuse, b_fuse, u_ws, v_ws);
    k_cols<<<dim3(256), dim3(256), 0, stream>>>(edges, u_ws, v_ws,
        W_ffn, b_ffn, Gd_ws, cnt_ws);

    if (ws_size >= need2){
        float* Sws = Pws + p2;
        float* Tws = Sws + s2;
        k_main<2><<<dim3(1024), dim3(256), 0, stream>>>(prev, edges, u_ws, v_ws,
            Gd_ws, W_ffn, W_fcc, b_fcc, Pws, Sws, Tws);
        k_merge<2><<<dim3(512), dim3(256), 0, stream>>>(Pws, Sws, Tws, Gd_ws,
            cnt_ws, W_ffn, W_fcg, b_fcg, out);
    } else {
        const size_t p1 = p2/2, s1 = s2/2;
        float* Sws = Pws + p1;
        float* Tws = Sws + s1;
        k_main<1><<<dim3(512), dim3(256), 0, stream>>>(prev, edges, u_ws, v_ws,
            Gd_ws, W_ffn, W_fcc, b_fcc, Pws, Sws, Tws);
        k_merge<1><<<dim3(512), dim3(256), 0, stream>>>(Pws, Sws, Tws, Gd_ws,
            cnt_ws, W_ffn, W_fcg, b_fcg, out);
    }
}

// Round 9
// 124.744 us; speedup vs baseline: 1.3080x; 1.3080x over previous
//
#include <hip/hip_runtime.h>

// ---------------------------------------------------------------------------
// B=4, N1=1024, N2=1024, D=256, H=4, Dh=64
//   u[b,i,4] = gelu(prev@W_pre+b_pre) @ W_fuse[0:6]
//   v[b,j,4] = gelu(curr@W_cur+b_cur) @ W_fuse[6:12] + b_fuse
//   c = mask ? u_i+v_j : 0
//   Gd_j[8] = gelu(d_j)@W_ffn[4:8] + gelu(e_j)@W_ffn[8:12] + b_ffn
//   logits = gelu(gelu(c)@W_ffn[0:4] + Gd_j)@W_fcc + b_fcc
//   softmax over i WITHOUT max-subtraction (logits bounded; masked -> exp=0)
//   res = P @ prev (per-head);  g_j = (T_j@W_ffn[0:4]+cnt*Gd_j)/(cnt+1)
//   out = res + gelu(g)@W_fcg + b_fcg
// Round-7 lesson: 1 col/thread -> 8x VMEM instrs, latency-bound (155us).
//   Balance: acc[4][8] (4 cols x 8 dims), 4-way row-split, ONE final merge.
// Round-6 lesson: softmax denominators are PER (column, HEAD).
// Round-5 lesson: acc[8][8]/thread -> VGPR=136 (over 128 cliff).
// Round-4 lesson: never cap __launch_bounds__ min-waves (spill -> HBM).
// ---------------------------------------------------------------------------

__device__ __forceinline__ float gelu_f(float x){
    float x3 = x*x*x;
    float t2 = 1.5957691216057308f * (x + 0.044715f*x3);
    float e  = __expf(t2);
    return x - __fdividef(x, e + 1.0f);
}

// ---- kernel 1: per-row u (prev side) and v (curr side), one wave per row ----
__global__ __launch_bounds__(256) void k_rows(
    const float* __restrict__ prev, const float* __restrict__ curr,
    const float* __restrict__ W_pre, const float* __restrict__ b_pre,
    const float* __restrict__ W_cur, const float* __restrict__ b_cur,
    const float* __restrict__ W_fuse, const float* __restrict__ b_fuse,
    float* __restrict__ u_ws, float* __restrict__ v_ws)
{
    int gid  = blockIdx.x * 256 + threadIdx.x;
    int wave = gid >> 6;
    int lane = threadIdx.x & 63;
    bool isPrev = wave < 4096;
    int row = isPrev ? wave : (wave - 4096);
    const float* xrow = (isPrev ? prev : curr) + (size_t)row * 256;
    const float* W  = isPrev ? W_pre : W_cur;
    const float* bv = isPrev ? b_pre : b_cur;

    float4 x4 = *reinterpret_cast<const float4*>(xrow + lane*4);
    const float* Wl = W + lane*24;
    float p[6];
    #pragma unroll
    for (int k=0;k<6;++k)
        p[k] = x4.x*Wl[k] + x4.y*Wl[6+k] + x4.z*Wl[12+k] + x4.w*Wl[18+k];
    #pragma unroll
    for (int off=32; off>=1; off>>=1){
        #pragma unroll
        for (int k=0;k<6;++k) p[k] += __shfl_xor(p[k], off, 64);
    }
    if (lane == 0){
        float g[6];
        #pragma unroll
        for(int k=0;k<6;++k) g[k] = gelu_f(p[k] + bv[k]);
        int rb = isPrev ? 0 : 6;
        float o[4];
        #pragma unroll
        for(int kk=0;kk<4;++kk){
            float a = isPrev ? 0.0f : b_fuse[kk];
            #pragma unroll
            for(int k=0;k<6;++k) a += g[k]*W_fuse[(rb+k)*4+kk];
            o[kk]=a;
        }
        float* dst = (isPrev ? u_ws : v_ws) + (size_t)row*4;
        *reinterpret_cast<float4*>(dst) = make_float4(o[0],o[1],o[2],o[3]);
    }
}

// ---- kernel 2: per-column reductions over edges + Gd precompute ----
__global__ __launch_bounds__(256) void k_cols(
    const int* __restrict__ edges,
    const float* __restrict__ u_ws, const float* __restrict__ v_ws,
    const float* __restrict__ W_ffn, const float* __restrict__ b_ffn,
    float* __restrict__ Gd_ws, float* __restrict__ cnt_ws)
{
    int b  = blockIdx.x >> 6;
    int j0 = (blockIdx.x & 63) * 16;
    int t  = threadIdx.x;
    int jq = t & 3, sl = t >> 2;
    const int*   eb = edges + (size_t)b*1048576 + j0 + jq*4;
    const float* ub = u_ws + (size_t)b*4096;

    int   cnt[4] = {0,0,0,0};
    float S[4][4] = {{0.f}};
    float M[4][4];
    #pragma unroll
    for (int q=0;q<4;++q)
        #pragma unroll
        for (int k=0;k<4;++k) M[q][k] = -3.4e38f;

    #pragma unroll 4
    for (int ii=0; ii<16; ++ii){
        int i = sl*16 + ii;
        int4   e4 = *reinterpret_cast<const int4*>(eb + (size_t)i*1024);
        float4 u4 = *reinterpret_cast<const float4*>(ub + i*4);
        float uu[4] = {u4.x,u4.y,u4.z,u4.w};
        int   ee[4] = {e4.x,e4.y,e4.z,e4.w};
        #pragma unroll
        for (int q=0;q<4;++q){
            bool mk = ee[q]!=0;
            cnt[q] += mk ? 1 : 0;
            #pragma unroll
            for (int k=0;k<4;++k){
                S[q][k] += mk ? uu[k] : 0.0f;
                M[q][k]  = mk ? fmaxf(M[q][k],uu[k]) : M[q][k];
            }
        }
    }
    __shared__ float rS[64][16][4];
    __shared__ float rM[64][16][4];
    __shared__ int   rC[64][16];
    #pragma unroll
    for (int q=0;q<4;++q){
        int c = jq*4+q;
        #pragma unroll
        for (int k=0;k<4;++k){ rS[sl][c][k]=S[q][k]; rM[sl][c][k]=M[q][k]; }
        rC[sl][c]=cnt[q];
    }
    __syncthreads();
    float aS[4], aM[4]; int aC=0; int c2=0, hf=0;
    if (t < 128){
        c2 = t & 15; hf = t >> 4;
        #pragma unroll
        for(int k=0;k<4;++k){ aS[k]=0.f; aM[k]=-3.4e38f; }
        for (int s2=hf*8; s2<hf*8+8; ++s2){
            aC += rC[s2][c2];
            #pragma unroll
            for(int k=0;k<4;++k){ aS[k]+=rS[s2][c2][k]; aM[k]=fmaxf(aM[k],rM[s2][c2][k]); }
        }
    }
    __syncthreads();
    if (t < 128){
        rC[hf][c2]=aC;
        #pragma unroll
        for(int k=0;k<4;++k){ rS[hf][c2][k]=aS[k]; rM[hf][c2][k]=aM[k]; }
    }
    __syncthreads();
    if (t < 16){
        int cc=0; float Sa[4]={0,0,0,0};
        float Ma[4]={-3.4e38f,-3.4e38f,-3.4e38f,-3.4e38f};
        for (int s2=0;s2<8;++s2){
            cc += rC[s2][t];
            #pragma unroll
            for(int k=0;k<4;++k){ Sa[k]+=rS[s2][t][k]; Ma[k]=fmaxf(Ma[k],rM[s2][t][k]); }
        }
        size_t cj = (size_t)b*1024 + j0 + t;
        float4 v4 = *reinterpret_cast<const float4*>(v_ws + cj*4);
        float vv[4]={v4.x,v4.y,v4.z,v4.w};
        float cf = (float)cc, e1 = cf + 1.0f;
        float gd[4], ge[4];
        #pragma unroll
        for(int k=0;k<4;++k){
            float dk = (Sa[k] + cf*vv[k]) / e1;
            float ek;
            if (cc == 0) ek = 0.0f;
            else { float m1 = Ma[k]+vv[k]; ek = (cc < 1024) ? fmaxf(m1, 0.0f) : m1; }
            gd[k]=gelu_f(dk); ge[k]=gelu_f(ek);
        }
        #pragma unroll
        for(int kk=0;kk<8;++kk){
            float a = b_ffn[kk];
            #pragma unroll
            for(int k=0;k<4;++k)
                a += gd[k]*W_ffn[(4+k)*8+kk] + ge[k]*W_ffn[(8+k)*8+kk];
            Gd_ws[cj*8+kk]=a;
        }
        cnt_ws[cj]=cf;
    }
}

// ---- kernel 3: logits + exp-sum + weighted prev; writes partials ----
// Block = (b, jtile of 8 cols, sp i-part). 256 threads, grid 4*128*SPLIT.
// Logit role: (il_w=t>>3 in 0..31, jl_w=t&7).
// PV role:    (jh=t&1: 4-col group, h=(t>>1)&3, dq=(t>>3)&7, ig=t>>6 row-qtr)
//   thread: 4 cols (jh*4..+4) x 8 dims (h*64+dq*8..+8), rows ig*16..+16/chunk.
//   acc[4][8]+s4[4]; ONE final 4-way ig-merge via LDS (plain sums, no-max SM).
template<int SPLIT>
__global__ __launch_bounds__(256) void k_main(
    const float* __restrict__ prev, const int* __restrict__ edges,
    const float* __restrict__ u_ws, const float* __restrict__ v_ws,
    const float* __restrict__ Gd_ws,
    const float* __restrict__ W_ffn, const float* __restrict__ W_fcc,
    const float* __restrict__ b_fcc,
    float* __restrict__ Pws, float* __restrict__ Sws, float* __restrict__ Tws)
{
    int bid = blockIdx.x;
    int sp  = bid & (SPLIT-1);
    int jt  = (bid / SPLIT) & 127;
    int b   = bid / (SPLIT*128);
    int j0  = jt*8;
    int t   = threadIdx.x;
    int jl_w = t & 7, il_w = t >> 3;
    int jh = t & 1, h = (t >> 1) & 3, dq = (t >> 3) & 7, ig = t >> 6;

    __shared__ __align__(16) float sBuf[7104]; // sLog 64*36=2304 / merge 3*64*37
    __shared__ float sU[64][4];
    __shared__ float sV[8][4];
    __shared__ float sGd[8][8];
    float* sLog = sBuf;

    if (t < 32) (&sV[0][0])[t]  = v_ws[((size_t)b*1024 + j0)*4 + t];
    if (t < 64) (&sGd[0][0])[t] = Gd_ws[((size_t)b*1024 + j0)*8 + t];

    // uniform weights -> scalar regs
    float W4r[4][8], Wfc[8][4], bfc[4];
    #pragma unroll
    for(int k=0;k<4;++k)
        #pragma unroll
        for(int kk=0;kk<8;++kk) W4r[k][kk]=W_ffn[k*8+kk];
    #pragma unroll
    for(int kk=0;kk<8;++kk)
        #pragma unroll
        for(int hh=0;hh<4;++hh) Wfc[kk][hh]=W_fcc[kk*4+hh];
    #pragma unroll
    for(int hh=0;hh<4;++hh) bfc[hh]=b_fcc[hh];

    float s4[4] = {0,0,0,0};
    float acc[4][8] = {{0,0,0,0,0,0,0,0},{0,0,0,0,0,0,0,0},
                       {0,0,0,0,0,0,0,0},{0,0,0,0,0,0,0,0}};
    float Tp[4] = {0,0,0,0};

    const int*   ebase  = edges + (size_t)b*1048576 + j0;
    const float* pbBase = prev  + (size_t)b*262144 + h*64 + dq*8;

    const int NCH = 16/SPLIT;
    for (int cc=0; cc<NCH; ++cc){
        int i0 = sp*(1024/SPLIT) + cc*64;
        __syncthreads();
        (&sU[0][0])[t] = u_ws[((size_t)b*1024 + i0)*4 + t];
        __syncthreads();

        // ---- logit phase: 512 pairs, 2 per thread ----
        #pragma unroll
        for (int r=0;r<2;++r){
            int il = il_w + 32*r;
            int eg = ebase[(size_t)(i0+il)*1024 + jl_w];
            float gc[4];
            #pragma unroll
            for(int k=0;k<4;++k){
                float ccv = sU[il][k] + sV[jl_w][k];
                gc[k] = gelu_f(ccv);
                Tp[k] += eg ? gc[k] : 0.0f;
            }
            float fu[8];
            #pragma unroll
            for(int kk=0;kk<8;++kk){
                float a = sGd[jl_w][kk];
                #pragma unroll
                for(int k=0;k<4;++k) a += gc[k]*W4r[k][kk];
                fu[kk] = gelu_f(a);
            }
            #pragma unroll
            for(int hh=0;hh<4;++hh){
                float a = bfc[hh];
                #pragma unroll
                for(int kk=0;kk<8;++kk) a += fu[kk]*Wfc[kk][hh];
                sLog[il*36 + hh*8 + jl_w] = eg ? a : -1e30f;
            }
        }
        __syncthreads();

        // ---- PV: rows ig*16..+16, cols jh*4..+4, dims h*64+dq*8..+8 ----
        const float* pc = pbBase + (size_t)(i0 + ig*16)*256;
        const float* lg = sLog + (ig*16)*36 + h*8 + jh*4;
        #pragma unroll 4
        for (int i=0;i<16;++i){
            float4 lv = *reinterpret_cast<const float4*>(lg + i*36);
            float w0 = __expf(lv.x), w1 = __expf(lv.y);
            float w2 = __expf(lv.z), w3 = __expf(lv.w);
            float4 a0 = *reinterpret_cast<const float4*>(pc + (size_t)i*256);
            float4 a1 = *reinterpret_cast<const float4*>(pc + (size_t)i*256 + 4);
            s4[0]+=w0; s4[1]+=w1; s4[2]+=w2; s4[3]+=w3;
            acc[0][0]+=w0*a0.x; acc[0][1]+=w0*a0.y; acc[0][2]+=w0*a0.z; acc[0][3]+=w0*a0.w;
            acc[0][4]+=w0*a1.x; acc[0][5]+=w0*a1.y; acc[0][6]+=w0*a1.z; acc[0][7]+=w0*a1.w;
            acc[1][0]+=w1*a0.x; acc[1][1]+=w1*a0.y; acc[1][2]+=w1*a0.z; acc[1][3]+=w1*a0.w;
            acc[1][4]+=w1*a1.x; acc[1][5]+=w1*a1.y; acc[1][6]+=w1*a1.z; acc[1][7]+=w1*a1.w;
            acc[2][0]+=w2*a0.x; acc[2][1]+=w2*a0.y; acc[2][2]+=w2*a0.z; acc[2][3]+=w2*a0.w;
            acc[2][4]+=w2*a1.x; acc[2][5]+=w2*a1.y; acc[2][6]+=w2*a1.z; acc[2][7]+=w2*a1.w;
            acc[3][0]+=w3*a0.x; acc[3][1]+=w3*a0.y; acc[3][2]+=w3*a0.z; acc[3][3]+=w3*a0.w;
            acc[3][4]+=w3*a1.x; acc[3][5]+=w3*a1.y; acc[3][6]+=w3*a1.z; acc[3][7]+=w3*a1.w;
        }
    }

    // ---- final 4-way merge across ig (plain sums) ----
    __syncthreads();
    if (ig > 0){
        float* dst = sBuf + (size_t)((ig-1)*64 + (t & 63))*37;
        #pragma unroll
        for (int c=0;c<4;++c) dst[c] = s4[c];
        #pragma unroll
        for (int c=0;c<4;++c)
            #pragma unroll
            for (int d=0;d<8;++d) dst[4 + c*8 + d] = acc[c][d];
    }
    __syncthreads();
    if (ig == 0){
        #pragma unroll
        for (int g=0; g<3; ++g){
            const float* src = sBuf + (size_t)(g*64 + t)*37;
            #pragma unroll
            for (int c=0;c<4;++c) s4[c] += src[c];
            #pragma unroll
            for (int c=0;c<4;++c)
                #pragma unroll
                for (int d=0;d<8;++d) acc[c][d] += src[4 + c*8 + d];
        }
    }

    size_t bp = ((size_t)b*128 + jt)*SPLIT + sp;

    // ---- T reduction (sBuf reused; barrier separates from merge reads) ----
    __syncthreads();
    #pragma unroll
    for (int k=0;k<4;++k) sBuf[(il_w*8 + jl_w)*4 + k] = Tp[k];
    __syncthreads();
    if (t < 8){
        float T0=0,T1=0,T2=0,T3=0;
        for (int s2=0;s2<32;++s2){
            const float* p = sBuf + (s2*8+t)*4;
            T0+=p[0];T1+=p[1];T2+=p[2];T3+=p[3];
        }
        float* td = Tws + (bp*8 + t)*4;
        td[0]=T0; td[1]=T1; td[2]=T2; td[3]=T3;
    }

    // ---- partial outputs from ig==0 threads (t<64) ----
    if (ig == 0){
        if (dq == 0){                       // t = h*2+jh < 8
            #pragma unroll
            for (int c=0;c<4;++c)
                Sws[bp*32 + h*8 + jh*4 + c] = s4[c];
        }
        #pragma unroll
        for (int c=0;c<4;++c){
            float* dst = Pws + (((size_t)bp*8 + jh*4 + c)*32 + h*8 + dq)*8;
            float4* d4 = reinterpret_cast<float4*>(dst);
            d4[0] = make_float4(acc[c][0],acc[c][1],acc[c][2],acc[c][3]);
            d4[1] = make_float4(acc[c][4],acc[c][5],acc[c][6],acc[c][7]);
        }
    }
}

// ---- kernel 4: merge split partials, normalize, add gelu(g)@W_fcg ----
// Block = (b, jtile of 8 cols), grid 512. Thread: jl=t>>5, hd=t&31
// (h=hd>>3, dq=hd&7) -> Pws read is linear in t (coalesced).
template<int SPLIT>
__global__ __launch_bounds__(256) void k_merge(
    const float* __restrict__ Pws, const float* __restrict__ Sws,
    const float* __restrict__ Tws,
    const float* __restrict__ Gd_ws, const float* __restrict__ cnt_ws,
    const float* __restrict__ W_ffn, const float* __restrict__ W_fcg,
    const float* __restrict__ b_fcg, float* __restrict__ out)
{
    int b  = blockIdx.x >> 7;
    int jt = blockIdx.x & 127;
    int j0 = jt*8;
    int t  = threadIdx.x;
    int jl = t >> 5, hd = t & 31, h = hd >> 3, dq = hd & 7;
    __shared__ float sG[8][8];

    size_t bp0 = ((size_t)b*128 + jt)*SPLIT;
    float s = 0.0f, acc[8] = {0,0,0,0,0,0,0,0};
    #pragma unroll
    for (int sp2=0; sp2<SPLIT; ++sp2){
        const float* p = Pws + ((bp0+sp2)*256 + t)*8;
        float4 p0 = *reinterpret_cast<const float4*>(p);
        float4 p1 = *reinterpret_cast<const float4*>(p+4);
        acc[0]+=p0.x; acc[1]+=p0.y; acc[2]+=p0.z; acc[3]+=p0.w;
        acc[4]+=p1.x; acc[5]+=p1.y; acc[6]+=p1.z; acc[7]+=p1.w;
        s += Sws[(bp0+sp2)*32 + h*8 + jl];
    }
    if (t < 8){
        float T[4] = {0,0,0,0};
        #pragma unroll
        for (int sp2=0; sp2<SPLIT; ++sp2){
            const float* tp = Tws + ((bp0+sp2)*8 + t)*4;
            #pragma unroll
            for (int k=0;k<4;++k) T[k]+=tp[k];
        }
        size_t cj = (size_t)b*1024 + j0 + t;
        float cf = cnt_ws[cj];
        float inv = __fdividef(1.0f, cf + 1.0f);
        #pragma unroll
        for (int kk=0;kk<8;++kk){
            float a = cf*Gd_ws[cj*8+kk];
            #pragma unroll
            for (int k=0;k<4;++k) a += T[k]*W_ffn[k*8+kk];
            sG[t][kk] = gelu_f(a*inv);
        }
    }
    __syncthreads();

    float rs = (s > 0.0f) ? (1.0f/s) : 0.0f;
    int col0 = h*64 + dq*8;
    float gg[8];
    #pragma unroll
    for (int kk=0;kk<8;++kk) gg[kk]=sG[jl][kk];
    float o[8];
    #pragma unroll
    for (int d2=0;d2<8;++d2){
        float a = b_fcg[col0+d2];
        #pragma unroll
        for (int kk=0;kk<8;++kk) a += gg[kk]*W_fcg[kk*256 + col0 + d2];
        o[d2] = acc[d2]*rs + a;
    }
    float* ob = out + ((size_t)b*1024 + j0 + jl)*256 + col0;
    float4* o4 = reinterpret_cast<float4*>(ob);
    o4[0] = make_float4(o[0],o[1],o[2],o[3]);
    o4[1] = make_float4(o[4],o[5],o[6],o[7]);
}

extern "C" void kernel_launch(void* const* d_in, const int* in_sizes, int n_in,
                              void* d_out, int out_size, void* d_ws, size_t ws_size,
                              hipStream_t stream)
{
    const float* prev  = (const float*)d_in[0];
    const float* curr  = (const float*)d_in[1];
    const int*   edges = (const int*)  d_in[2];
    const float* W_pre = (const float*)d_in[3];
    const float* b_pre = (const float*)d_in[4];
    const float* W_cur = (const float*)d_in[5];
    const float* b_cur = (const float*)d_in[6];
    const float* W_fuse= (const float*)d_in[7];
    const float* b_fuse= (const float*)d_in[8];
    const float* W_ffn = (const float*)d_in[9];
    const float* b_ffn = (const float*)d_in[10];
    const float* W_fcc = (const float*)d_in[11];
    const float* b_fcc = (const float*)d_in[12];
    const float* W_fcg = (const float*)d_in[13];
    const float* b_fcg = (const float*)d_in[14];
    float* out = (float*)d_out;

    float* u_ws   = (float*)d_ws;          // 16384 floats
    float* v_ws   = u_ws  + 16384;         // 16384
    float* Gd_ws  = v_ws  + 16384;         // 32768
    float* cnt_ws = Gd_ws + 32768;         // 4096
    float* Pws    = cnt_ws + 4096;
    const size_t base_f = 16384 + 16384 + 32768 + 4096;
    const size_t p2 = (size_t)4*128*2*256*8;            // 2,097,152 floats
    const size_t s2 = (size_t)4*128*2*32;               // 32,768
    const size_t t2 = (size_t)4*128*2*8*4;              // 32,768
    const size_t need2 = (base_f + p2 + s2 + t2) * 4;

    k_rows<<<dim3(2048), dim3(256), 0, stream>>>(prev, curr, W_pre, b_pre,
        W_cur, b_cur, W_fuse, b_fuse, u_ws, v_ws);
    k_cols<<<dim3(256), dim3(256), 0, stream>>>(edges, u_ws, v_ws,
        W_ffn, b_ffn, Gd_ws, cnt_ws);

    if (ws_size >= need2){
        float* Sws = Pws + p2;
        float* Tws = Sws + s2;
        k_main<2><<<dim3(1024), dim3(256), 0, stream>>>(prev, edges, u_ws, v_ws,
            Gd_ws, W_ffn, W_fcc, b_fcc, Pws, Sws, Tws);
        k_merge<2><<<dim3(512), dim3(256), 0, stream>>>(Pws, Sws, Tws, Gd_ws,
            cnt_ws, W_ffn, W_fcg, b_fcg, out);
    } else {
        const size_t p1 = p2/2, s1 = s2/2;
        float* Sws = Pws + p1;
        float* Tws = Sws + s1;
        k_main<1><<<dim3(512), dim3(256), 0, stream>>>(prev, edges, u_ws, v_ws,
            Gd_ws, W_ffn, W_fcc, b_fcc, Pws, Sws, Tws);
        k_merge<1><<<dim3(512), dim3(256), 0, stream>>>(Pws, Sws, Tws, Gd_ws,
            cnt_ws, W_ffn, W_fcg, b_fcg, out);
    }
}

// Round 10
// 113.762 us; speedup vs baseline: 1.4342x; 1.0965x over previous
//
#include <hip/hip_runtime.h>

// ---------------------------------------------------------------------------
// B=4, N1=1024, N2=1024, D=256, H=4, Dh=64
//   u[b,i,4] = gelu(prev@W_pre+b_pre) @ W_fuse[0:6]
//   v[b,j,4] = gelu(curr@W_cur+b_cur) @ W_fuse[6:12] + b_fuse
//   c = mask ? u_i+v_j : 0
//   Gd_j[8] = gelu(d_j)@W_ffn[4:8] + gelu(e_j)@W_ffn[8:12] + b_ffn
//   logits = gelu(gelu(c)@W_ffn[0:4] + Gd_j)@W_fcc + b_fcc
//   softmax over i WITHOUT max-subtraction (logits bounded; masked -> w=0)
//   res = P @ prev (per-head);  g_j = (T_j@W_ffn[0:4]+cnt*Gd_j)/(cnt+1)
//   out = res + gelu(g)@W_fcg + b_fcg
// Round-9 lesson: PV exp'd each logit 8x (8 dq threads share one sLog addr).
//   Store w=exp(logit) at WRITE time -> PV is pure FMA; 8x fewer PV trans ops.
// Round-7 lesson: 1 col/thread -> 8x VMEM, latency-bound. acc[4][8] balance.
// Round-6 lesson: softmax denominators are PER (column, HEAD).
// Round-5 lesson: acc[8][8]/thread -> VGPR=136 (over 128 cliff).
// Round-4 lesson: never cap __launch_bounds__ min-waves (spill -> HBM).
// ---------------------------------------------------------------------------

__device__ __forceinline__ float gelu_f(float x){
    float x3 = x*x*x;
    float t2 = 1.5957691216057308f * (x + 0.044715f*x3);
    float e  = __expf(t2);
    return x - __fdividef(x, e + 1.0f);
}

// ---- kernel 1: per-row u (prev side) and v (curr side), one wave per row ----
__global__ __launch_bounds__(256) void k_rows(
    const float* __restrict__ prev, const float* __restrict__ curr,
    const float* __restrict__ W_pre, const float* __restrict__ b_pre,
    const float* __restrict__ W_cur, const float* __restrict__ b_cur,
    const float* __restrict__ W_fuse, const float* __restrict__ b_fuse,
    float* __restrict__ u_ws, float* __restrict__ v_ws)
{
    int gid  = blockIdx.x * 256 + threadIdx.x;
    int wave = gid >> 6;
    int lane = threadIdx.x & 63;
    bool isPrev = wave < 4096;
    int row = isPrev ? wave : (wave - 4096);
    const float* xrow = (isPrev ? prev : curr) + (size_t)row * 256;
    const float* W  = isPrev ? W_pre : W_cur;
    const float* bv = isPrev ? b_pre : b_cur;

    float4 x4 = *reinterpret_cast<const float4*>(xrow + lane*4);
    const float* Wl = W + lane*24;
    float p[6];
    #pragma unroll
    for (int k=0;k<6;++k)
        p[k] = x4.x*Wl[k] + x4.y*Wl[6+k] + x4.z*Wl[12+k] + x4.w*Wl[18+k];
    #pragma unroll
    for (int off=32; off>=1; off>>=1){
        #pragma unroll
        for (int k=0;k<6;++k) p[k] += __shfl_xor(p[k], off, 64);
    }
    if (lane == 0){
        float g[6];
        #pragma unroll
        for(int k=0;k<6;++k) g[k] = gelu_f(p[k] + bv[k]);
        int rb = isPrev ? 0 : 6;
        float o[4];
        #pragma unroll
        for(int kk=0;kk<4;++kk){
            float a = isPrev ? 0.0f : b_fuse[kk];
            #pragma unroll
            for(int k=0;k<6;++k) a += g[k]*W_fuse[(rb+k)*4+kk];
            o[kk]=a;
        }
        float* dst = (isPrev ? u_ws : v_ws) + (size_t)row*4;
        *reinterpret_cast<float4*>(dst) = make_float4(o[0],o[1],o[2],o[3]);
    }
}

// ---- kernel 2: per-column reductions over edges + Gd precompute ----
__global__ __launch_bounds__(256) void k_cols(
    const int* __restrict__ edges,
    const float* __restrict__ u_ws, const float* __restrict__ v_ws,
    const float* __restrict__ W_ffn, const float* __restrict__ b_ffn,
    float* __restrict__ Gd_ws, float* __restrict__ cnt_ws)
{
    int b  = blockIdx.x >> 6;
    int j0 = (blockIdx.x & 63) * 16;
    int t  = threadIdx.x;
    int jq = t & 3, sl = t >> 2;
    const int*   eb = edges + (size_t)b*1048576 + j0 + jq*4;
    const float* ub = u_ws + (size_t)b*4096;

    int   cnt[4] = {0,0,0,0};
    float S[4][4] = {{0.f}};
    float M[4][4];
    #pragma unroll
    for (int q=0;q<4;++q)
        #pragma unroll
        for (int k=0;k<4;++k) M[q][k] = -3.4e38f;

    #pragma unroll 4
    for (int ii=0; ii<16; ++ii){
        int i = sl*16 + ii;
        int4   e4 = *reinterpret_cast<const int4*>(eb + (size_t)i*1024);
        float4 u4 = *reinterpret_cast<const float4*>(ub + i*4);
        float uu[4] = {u4.x,u4.y,u4.z,u4.w};
        int   ee[4] = {e4.x,e4.y,e4.z,e4.w};
        #pragma unroll
        for (int q=0;q<4;++q){
            bool mk = ee[q]!=0;
            cnt[q] += mk ? 1 : 0;
            #pragma unroll
            for (int k=0;k<4;++k){
                S[q][k] += mk ? uu[k] : 0.0f;
                M[q][k]  = mk ? fmaxf(M[q][k],uu[k]) : M[q][k];
            }
        }
    }
    __shared__ float rS[64][16][4];
    __shared__ float rM[64][16][4];
    __shared__ int   rC[64][16];
    #pragma unroll
    for (int q=0;q<4;++q){
        int c = jq*4+q;
        #pragma unroll
        for (int k=0;k<4;++k){ rS[sl][c][k]=S[q][k]; rM[sl][c][k]=M[q][k]; }
        rC[sl][c]=cnt[q];
    }
    __syncthreads();
    float aS[4], aM[4]; int aC=0; int c2=0, hf=0;
    if (t < 128){
        c2 = t & 15; hf = t >> 4;
        #pragma unroll
        for(int k=0;k<4;++k){ aS[k]=0.f; aM[k]=-3.4e38f; }
        for (int s2=hf*8; s2<hf*8+8; ++s2){
            aC += rC[s2][c2];
            #pragma unroll
            for(int k=0;k<4;++k){ aS[k]+=rS[s2][c2][k]; aM[k]=fmaxf(aM[k],rM[s2][c2][k]); }
        }
    }
    __syncthreads();
    if (t < 128){
        rC[hf][c2]=aC;
        #pragma unroll
        for(int k=0;k<4;++k){ rS[hf][c2][k]=aS[k]; rM[hf][c2][k]=aM[k]; }
    }
    __syncthreads();
    if (t < 16){
        int cc=0; float Sa[4]={0,0,0,0};
        float Ma[4]={-3.4e38f,-3.4e38f,-3.4e38f,-3.4e38f};
        for (int s2=0;s2<8;++s2){
            cc += rC[s2][t];
            #pragma unroll
            for(int k=0;k<4;++k){ Sa[k]+=rS[s2][t][k]; Ma[k]=fmaxf(Ma[k],rM[s2][t][k]); }
        }
        size_t cj = (size_t)b*1024 + j0 + t;
        float4 v4 = *reinterpret_cast<const float4*>(v_ws + cj*4);
        float vv[4]={v4.x,v4.y,v4.z,v4.w};
        float cf = (float)cc, e1 = cf + 1.0f;
        float gd[4], ge[4];
        #pragma unroll
        for(int k=0;k<4;++k){
            float dk = (Sa[k] + cf*vv[k]) / e1;
            float ek;
            if (cc == 0) ek = 0.0f;
            else { float m1 = Ma[k]+vv[k]; ek = (cc < 1024) ? fmaxf(m1, 0.0f) : m1; }
            gd[k]=gelu_f(dk); ge[k]=gelu_f(ek);
        }
        #pragma unroll
        for(int kk=0;kk<8;++kk){
            float a = b_ffn[kk];
            #pragma unroll
            for(int k=0;k<4;++k)
                a += gd[k]*W_ffn[(4+k)*8+kk] + ge[k]*W_ffn[(8+k)*8+kk];
            Gd_ws[cj*8+kk]=a;
        }
        cnt_ws[cj]=cf;
    }
}

// ---- kernel 3: logits -> w=exp(logit) in LDS; PV pure-FMA; partials out ----
// Block = (b, jtile of 8 cols, sp i-part). 256 threads, grid 4*128*SPLIT.
// Logit role: (il_w=t>>3 in 0..31, jl_w=t&7) -> writes w (exp applied ONCE).
// PV role:    (jh=t&1, h=(t>>1)&3, dq=(t>>3)&7, ig=t>>6): 4 cols x 8 dims,
//             rows ig*16..+16 per chunk. acc[4][8]+s4[4]; pairwise ig-merge.
template<int SPLIT>
__global__ __launch_bounds__(256) void k_main(
    const float* __restrict__ prev, const int* __restrict__ edges,
    const float* __restrict__ u_ws, const float* __restrict__ v_ws,
    const float* __restrict__ Gd_ws,
    const float* __restrict__ W_ffn, const float* __restrict__ W_fcc,
    const float* __restrict__ b_fcc,
    float* __restrict__ Pws, float* __restrict__ Sws, float* __restrict__ Tws)
{
    int bid = blockIdx.x;
    int sp  = bid & (SPLIT-1);
    int jt  = (bid / SPLIT) & 127;
    int b   = bid / (SPLIT*128);
    int j0  = jt*8;
    int t   = threadIdx.x;
    int jl_w = t & 7, il_w = t >> 3;
    int jh = t & 1, h = (t >> 1) & 3, dq = (t >> 3) & 7, ig = t >> 6;

    __shared__ __align__(16) float sBuf[4736]; // sLog 64*36=2304 / merge 2*64*37
    __shared__ float sU[64][4];
    __shared__ float sV[8][4];
    __shared__ float sGd[8][8];
    float* sLog = sBuf;

    if (t < 32) (&sV[0][0])[t]  = v_ws[((size_t)b*1024 + j0)*4 + t];
    if (t < 64) (&sGd[0][0])[t] = Gd_ws[((size_t)b*1024 + j0)*8 + t];

    // uniform weights -> scalar regs
    float W4r[4][8], Wfc[8][4], bfc[4];
    #pragma unroll
    for(int k=0;k<4;++k)
        #pragma unroll
        for(int kk=0;kk<8;++kk) W4r[k][kk]=W_ffn[k*8+kk];
    #pragma unroll
    for(int kk=0;kk<8;++kk)
        #pragma unroll
        for(int hh=0;hh<4;++hh) Wfc[kk][hh]=W_fcc[kk*4+hh];
    #pragma unroll
    for(int hh=0;hh<4;++hh) bfc[hh]=b_fcc[hh];

    float s4[4] = {0,0,0,0};
    float acc[4][8] = {{0,0,0,0,0,0,0,0},{0,0,0,0,0,0,0,0},
                       {0,0,0,0,0,0,0,0},{0,0,0,0,0,0,0,0}};
    float Tp[4] = {0,0,0,0};

    const int*   ebase  = edges + (size_t)b*1048576 + j0;
    const float* pbBase = prev  + (size_t)b*262144 + h*64 + dq*8;

    const int NCH = 16/SPLIT;
    for (int cc=0; cc<NCH; ++cc){
        int i0 = sp*(1024/SPLIT) + cc*64;
        __syncthreads();
        (&sU[0][0])[t] = u_ws[((size_t)b*1024 + i0)*4 + t];
        __syncthreads();

        // ---- logit phase: 512 pairs, 2 per thread; store w = exp(logit) ----
        #pragma unroll
        for (int r=0;r<2;++r){
            int il = il_w + 32*r;
            int eg = ebase[(size_t)(i0+il)*1024 + jl_w];
            float gc[4];
            #pragma unroll
            for(int k=0;k<4;++k){
                float ccv = sU[il][k] + sV[jl_w][k];
                gc[k] = gelu_f(ccv);
                Tp[k] += eg ? gc[k] : 0.0f;
            }
            float fu[8];
            #pragma unroll
            for(int kk=0;kk<8;++kk){
                float a = sGd[jl_w][kk];
                #pragma unroll
                for(int k=0;k<4;++k) a += gc[k]*W4r[k][kk];
                fu[kk] = gelu_f(a);
            }
            #pragma unroll
            for(int hh=0;hh<4;++hh){
                float a = bfc[hh];
                #pragma unroll
                for(int kk=0;kk<8;++kk) a += fu[kk]*Wfc[kk][hh];
                sLog[il*36 + hh*8 + jl_w] = eg ? __expf(a) : 0.0f;
            }
        }
        __syncthreads();

        // ---- PV: rows ig*16..+16, cols jh*4..+4, dims h*64+dq*8..+8 ----
        const float* pc = pbBase + (size_t)(i0 + ig*16)*256;
        const float* lg = sLog + (ig*16)*36 + h*8 + jh*4;
        #pragma unroll 4
        for (int i=0;i<16;++i){
            float4 lv = *reinterpret_cast<const float4*>(lg + i*36);
            float w0 = lv.x, w1 = lv.y, w2 = lv.z, w3 = lv.w;
            float4 a0 = *reinterpret_cast<const float4*>(pc + (size_t)i*256);
            float4 a1 = *reinterpret_cast<const float4*>(pc + (size_t)i*256 + 4);
            s4[0]+=w0; s4[1]+=w1; s4[2]+=w2; s4[3]+=w3;
            acc[0][0]+=w0*a0.x; acc[0][1]+=w0*a0.y; acc[0][2]+=w0*a0.z; acc[0][3]+=w0*a0.w;
            acc[0][4]+=w0*a1.x; acc[0][5]+=w0*a1.y; acc[0][6]+=w0*a1.z; acc[0][7]+=w0*a1.w;
            acc[1][0]+=w1*a0.x; acc[1][1]+=w1*a0.y; acc[1][2]+=w1*a0.z; acc[1][3]+=w1*a0.w;
            acc[1][4]+=w1*a1.x; acc[1][5]+=w1*a1.y; acc[1][6]+=w1*a1.z; acc[1][7]+=w1*a1.w;
            acc[2][0]+=w2*a0.x; acc[2][1]+=w2*a0.y; acc[2][2]+=w2*a0.z; acc[2][3]+=w2*a0.w;
            acc[2][4]+=w2*a1.x; acc[2][5]+=w2*a1.y; acc[2][6]+=w2*a1.z; acc[2][7]+=w2*a1.w;
            acc[3][0]+=w3*a0.x; acc[3][1]+=w3*a0.y; acc[3][2]+=w3*a0.z; acc[3][3]+=w3*a0.w;
            acc[3][4]+=w3*a1.x; acc[3][5]+=w3*a1.y; acc[3][6]+=w3*a1.z; acc[3][7]+=w3*a1.w;
        }
    }

    // ---- pairwise ig-merge (plain sums), buffer 2*64*37 floats ----
    int r64 = t & 63;
    __syncthreads();
    if (ig >= 2){
        float* dst = sBuf + (size_t)((ig-2)*64 + r64)*37;
        #pragma unroll
        for (int c=0;c<4;++c) dst[c] = s4[c];
        #pragma unroll
        for (int c=0;c<4;++c)
            #pragma unroll
            for (int d=0;d<8;++d) dst[4 + c*8 + d] = acc[c][d];
    }
    __syncthreads();
    if (ig < 2){
        const float* src = sBuf + (size_t)(ig*64 + r64)*37;
        #pragma unroll
        for (int c=0;c<4;++c) s4[c] += src[c];
        #pragma unroll
        for (int c=0;c<4;++c)
            #pragma unroll
            for (int d=0;d<8;++d) acc[c][d] += src[4 + c*8 + d];
    }
    __syncthreads();
    if (ig == 1){
        float* dst = sBuf + (size_t)r64*37;
        #pragma unroll
        for (int c=0;c<4;++c) dst[c] = s4[c];
        #pragma unroll
        for (int c=0;c<4;++c)
            #pragma unroll
            for (int d=0;d<8;++d) dst[4 + c*8 + d] = acc[c][d];
    }
    __syncthreads();
    if (ig == 0){
        const float* src = sBuf + (size_t)t*37;
        #pragma unroll
        for (int c=0;c<4;++c) s4[c] += src[c];
        #pragma unroll
        for (int c=0;c<4;++c)
            #pragma unroll
            for (int d=0;d<8;++d) acc[c][d] += src[4 + c*8 + d];
    }

    size_t bp = ((size_t)b*128 + jt)*SPLIT + sp;

    // ---- T reduction (sBuf reused; barrier separates from merge reads) ----
    __syncthreads();
    #pragma unroll
    for (int k=0;k<4;++k) sBuf[(il_w*8 + jl_w)*4 + k] = Tp[k];
    __syncthreads();
    if (t < 8){
        float T0=0,T1=0,T2=0,T3=0;
        for (int s2=0;s2<32;++s2){
            const float* p = sBuf + (s2*8+t)*4;
            T0+=p[0];T1+=p[1];T2+=p[2];T3+=p[3];
        }
        float* td = Tws + (bp*8 + t)*4;
        td[0]=T0; td[1]=T1; td[2]=T2; td[3]=T3;
    }

    // ---- partial outputs from ig==0 threads (t<64) ----
    if (ig == 0){
        if (dq == 0){                       // t = h*2+jh < 8
            #pragma unroll
            for (int c=0;c<4;++c)
                Sws[bp*32 + h*8 + jh*4 + c] = s4[c];
        }
        #pragma unroll
        for (int c=0;c<4;++c){
            float* dst = Pws + (((size_t)bp*8 + jh*4 + c)*32 + h*8 + dq)*8;
            float4* d4 = reinterpret_cast<float4*>(dst);
            d4[0] = make_float4(acc[c][0],acc[c][1],acc[c][2],acc[c][3]);
            d4[1] = make_float4(acc[c][4],acc[c][5],acc[c][6],acc[c][7]);
        }
    }
}

// ---- kernel 4: merge split partials, normalize, add gelu(g)@W_fcg ----
// Block = (b, jtile of 8 cols), grid 512. Thread: jl=t>>5, hd=t&31
// (h=hd>>3, dq=hd&7) -> Pws read is linear in t (coalesced).
template<int SPLIT>
__global__ __launch_bounds__(256) void k_merge(
    const float* __restrict__ Pws, const float* __restrict__ Sws,
    const float* __restrict__ Tws,
    const float* __restrict__ Gd_ws, const float* __restrict__ cnt_ws,
    const float* __restrict__ W_ffn, const float* __restrict__ W_fcg,
    const float* __restrict__ b_fcg, float* __restrict__ out)
{
    int b  = blockIdx.x >> 7;
    int jt = blockIdx.x & 127;
    int j0 = jt*8;
    int t  = threadIdx.x;
    int jl = t >> 5, hd = t & 31, h = hd >> 3, dq = hd & 7;
    __shared__ float sG[8][8];

    size_t bp0 = ((size_t)b*128 + jt)*SPLIT;
    float s = 0.0f, acc[8] = {0,0,0,0,0,0,0,0};
    #pragma unroll
    for (int sp2=0; sp2<SPLIT; ++sp2){
        const float* p = Pws + ((bp0+sp2)*256 + t)*8;
        float4 p0 = *reinterpret_cast<const float4*>(p);
        float4 p1 = *reinterpret_cast<const float4*>(p+4);
        acc[0]+=p0.x; acc[1]+=p0.y; acc[2]+=p0.z; acc[3]+=p0.w;
        acc[4]+=p1.x; acc[5]+=p1.y; acc[6]+=p1.z; acc[7]+=p1.w;
        s += Sws[(bp0+sp2)*32 + h*8 + jl];
    }
    if (t < 8){
        float T[4] = {0,0,0,0};
        #pragma unroll
        for (int sp2=0; sp2<SPLIT; ++sp2){
            const float* tp = Tws + ((bp0+sp2)*8 + t)*4;
            #pragma unroll
            for (int k=0;k<4;++k) T[k]+=tp[k];
        }
        size_t cj = (size_t)b*1024 + j0 + t;
        float cf = cnt_ws[cj];
        float inv = __fdividef(1.0f, cf + 1.0f);
        #pragma unroll
        for (int kk=0;kk<8;++kk){
            float a = cf*Gd_ws[cj*8+kk];
            #pragma unroll
            for (int k=0;k<4;++k) a += T[k]*W_ffn[k*8+kk];
            sG[t][kk] = gelu_f(a*inv);
        }
    }
    __syncthreads();

    float rs = (s > 0.0f) ? (1.0f/s) : 0.0f;
    int col0 = h*64 + dq*8;
    float gg[8];
    #pragma unroll
    for (int kk=0;kk<8;++kk) gg[kk]=sG[jl][kk];
    float o[8];
    #pragma unroll
    for (int d2=0;d2<8;++d2){
        float a = b_fcg[col0+d2];
        #pragma unroll
        for (int kk=0;kk<8;++kk) a += gg[kk]*W_fcg[kk*256 + col0 + d2];
        o[d2] = acc[d2]*rs + a;
    }
    float* ob = out + ((size_t)b*1024 + j0 + jl)*256 + col0;
    float4* o4 = reinterpret_cast<float4*>(ob);
    o4[0] = make_float4(o[0],o[1],o[2],o[3]);
    o4[1] = make_float4(o[4],o[5],o[6],o[7]);
}

extern "C" void kernel_launch(void* const* d_in, const int* in_sizes, int n_in,
                              void* d_out, int out_size, void* d_ws, size_t ws_size,
                              hipStream_t stream)
{
    const float* prev  = (const float*)d_in[0];
    const float* curr  = (const float*)d_in[1];
    const int*   edges = (const int*)  d_in[2];
    const float* W_pre = (const float*)d_in[3];
    const float* b_pre = (const float*)d_in[4];
    const float* W_cur = (const float*)d_in[5];
    const float* b_cur = (const float*)d_in[6];
    const float* W_fuse= (const float*)d_in[7];
    const float* b_fuse= (const float*)d_in[8];
    const float* W_ffn = (const float*)d_in[9];
    const float* b_ffn = (const float*)d_in[10];
    const float* W_fcc = (const float*)d_in[11];
    const float* b_fcc = (const float*)d_in[12];
    const float* W_fcg = (const float*)d_in[13];
    const float* b_fcg = (const float*)d_in[14];
    float* out = (float*)d_out;

    float* u_ws   = (float*)d_ws;          // 16384 floats
    float* v_ws   = u_ws  + 16384;         // 16384
    float* Gd_ws  = v_ws  + 16384;         // 32768
    float* cnt_ws = Gd_ws + 32768;         // 4096
    float* Pws    = cnt_ws + 4096;
    const size_t base_f = 16384 + 16384 + 32768 + 4096;

    k_rows<<<dim3(2048), dim3(256), 0, stream>>>(prev, curr, W_pre, b_pre,
        W_cur, b_cur, W_fuse, b_fuse, u_ws, v_ws);
    k_cols<<<dim3(256), dim3(256), 0, stream>>>(edges, u_ws, v_ws,
        W_ffn, b_ffn, Gd_ws, cnt_ws);

    const size_t p4 = (size_t)4*128*4*256*8, s4 = (size_t)4*128*4*32,
                 t4 = (size_t)4*128*4*8*4;
    const size_t p2 = p4/2, s2v = s4/2, t2 = t4/2;
    const size_t need4 = (base_f + p4 + s4 + t4) * 4;
    const size_t need2 = (base_f + p2 + s2v + t2) * 4;

    if (ws_size >= need4){
        float* Sws = Pws + p4;
        float* Tws = Sws + s4;
        k_main<4><<<dim3(2048), dim3(256), 0, stream>>>(prev, edges, u_ws, v_ws,
            Gd_ws, W_ffn, W_fcc, b_fcc, Pws, Sws, Tws);
        k_merge<4><<<dim3(512), dim3(256), 0, stream>>>(Pws, Sws, Tws, Gd_ws,
            cnt_ws, W_ffn, W_fcg, b_fcg, out);
    } else if (ws_size >= need2){
        float* Sws = Pws + p2;
        float* Tws = Sws + s2v;
        k_main<2><<<dim3(1024), dim3(256), 0, stream>>>(prev, edges, u_ws, v_ws,
            Gd_ws, W_ffn, W_fcc, b_fcc, Pws, Sws, Tws);
        k_merge<2><<<dim3(512), dim3(256), 0, stream>>>(Pws, Sws, Tws, Gd_ws,
            cnt_ws, W_ffn, W_fcg, b_fcg, out);
    } else {
        const size_t p1 = p4/4, s1 = s4/4;
        float* Sws = Pws + p1;
        float* Tws = Sws + s1;
        k_main<1><<<dim3(512), dim3(256), 0, stream>>>(prev, edges, u_ws, v_ws,
            Gd_ws, W_ffn, W_fcc, b_fcc, Pws, Sws, Tws);
        k_merge<1><<<dim3(512), dim3(256), 0, stream>>>(Pws, Sws, Tws, Gd_ws,
            cnt_ws, W_ffn, W_fcg, b_fcg, out);
    }
}

// Round 11
// 112.520 us; speedup vs baseline: 1.4500x; 1.0110x over previous
//
#include <hip/hip_runtime.h>

// ---------------------------------------------------------------------------
// B=4, N1=1024, N2=1024, D=256, H=4, Dh=64
//   u[b,i,4] = gelu(prev@W_pre+b_pre) @ W_fuse[0:6]
//   v[b,j,4] = gelu(curr@W_cur+b_cur) @ W_fuse[6:12] + b_fuse
//   c = mask ? u_i+v_j : 0
//   Gd_j[8] = gelu(d_j)@W_ffn[4:8] + gelu(e_j)@W_ffn[8:12] + b_ffn
//   logits = gelu(gelu(c)@W_ffn[0:4] + Gd_j)@W_fcc + b_fcc
//   softmax over i WITHOUT max-subtraction (masked -> w=0); plain-sum partials
//   res = P @ prev (per-head);  g_j = (T_j@W_ffn[0:4]+cnt*Gd_j)/(cnt+1)
//   out = res + gelu(g)@W_fcg + b_fcg
// Round-10 lesson: 3 barriers/chunk + exposed edges/sU latency + scalar PV
//   FMA -> 55% VALUBusy. Fix: v_pk_fma_f32 PV (float2), reg-prefetch next
//   chunk's edges+sU during logit, 2 barriers/chunk.
// Round-9 lesson: exp once at sLog-write (not 8x in PV).
// Round-7 lesson: 1 col/thread -> 8x VMEM, latency-bound. acc 4colsx8dims.
// Round-6 lesson: softmax denominators are PER (column, HEAD).
// Round-5 lesson: acc[8][8]/thread -> VGPR=136 (over 128 cliff).
// Round-4 lesson: never cap __launch_bounds__ min-waves (spill -> HBM).
// ---------------------------------------------------------------------------

typedef float v2f __attribute__((ext_vector_type(2)));
__device__ __forceinline__ v2f pk_fma(v2f a, v2f b, v2f c){
    return __builtin_elementwise_fma(a, b, c);
}

__device__ __forceinline__ float gelu_f(float x){
    float x3 = x*x*x;
    float t2 = 1.5957691216057308f * (x + 0.044715f*x3);
    float e  = __expf(t2);
    return x - __fdividef(x, e + 1.0f);
}

// ---- kernel 1: per-row u (prev side) and v (curr side), one wave per row ----
__global__ __launch_bounds__(256) void k_rows(
    const float* __restrict__ prev, const float* __restrict__ curr,
    const float* __restrict__ W_pre, const float* __restrict__ b_pre,
    const float* __restrict__ W_cur, const float* __restrict__ b_cur,
    const float* __restrict__ W_fuse, const float* __restrict__ b_fuse,
    float* __restrict__ u_ws, float* __restrict__ v_ws)
{
    int gid  = blockIdx.x * 256 + threadIdx.x;
    int wave = gid >> 6;
    int lane = threadIdx.x & 63;
    bool isPrev = wave < 4096;
    int row = isPrev ? wave : (wave - 4096);
    const float* xrow = (isPrev ? prev : curr) + (size_t)row * 256;
    const float* W  = isPrev ? W_pre : W_cur;
    const float* bv = isPrev ? b_pre : b_cur;

    float4 x4 = *reinterpret_cast<const float4*>(xrow + lane*4);
    const float* Wl = W + lane*24;
    float p[6];
    #pragma unroll
    for (int k=0;k<6;++k)
        p[k] = x4.x*Wl[k] + x4.y*Wl[6+k] + x4.z*Wl[12+k] + x4.w*Wl[18+k];
    #pragma unroll
    for (int off=32; off>=1; off>>=1){
        #pragma unroll
        for (int k=0;k<6;++k) p[k] += __shfl_xor(p[k], off, 64);
    }
    if (lane == 0){
        float g[6];
        #pragma unroll
        for(int k=0;k<6;++k) g[k] = gelu_f(p[k] + bv[k]);
        int rb = isPrev ? 0 : 6;
        float o[4];
        #pragma unroll
        for(int kk=0;kk<4;++kk){
            float a = isPrev ? 0.0f : b_fuse[kk];
            #pragma unroll
            for(int k=0;k<6;++k) a += g[k]*W_fuse[(rb+k)*4+kk];
            o[kk]=a;
        }
        float* dst = (isPrev ? u_ws : v_ws) + (size_t)row*4;
        *reinterpret_cast<float4*>(dst) = make_float4(o[0],o[1],o[2],o[3]);
    }
}

// ---- kernel 2: per-column reductions over edges + Gd precompute ----
__global__ __launch_bounds__(256) void k_cols(
    const int* __restrict__ edges,
    const float* __restrict__ u_ws, const float* __restrict__ v_ws,
    const float* __restrict__ W_ffn, const float* __restrict__ b_ffn,
    float* __restrict__ Gd_ws, float* __restrict__ cnt_ws)
{
    int b  = blockIdx.x >> 6;
    int j0 = (blockIdx.x & 63) * 16;
    int t  = threadIdx.x;
    int jq = t & 3, sl = t >> 2;
    const int*   eb = edges + (size_t)b*1048576 + j0 + jq*4;
    const float* ub = u_ws + (size_t)b*4096;

    int   cnt[4] = {0,0,0,0};
    float S[4][4] = {{0.f}};
    float M[4][4];
    #pragma unroll
    for (int q=0;q<4;++q)
        #pragma unroll
        for (int k=0;k<4;++k) M[q][k] = -3.4e38f;

    #pragma unroll 4
    for (int ii=0; ii<16; ++ii){
        int i = sl*16 + ii;
        int4   e4 = *reinterpret_cast<const int4*>(eb + (size_t)i*1024);
        float4 u4 = *reinterpret_cast<const float4*>(ub + i*4);
        float uu[4] = {u4.x,u4.y,u4.z,u4.w};
        int   ee[4] = {e4.x,e4.y,e4.z,e4.w};
        #pragma unroll
        for (int q=0;q<4;++q){
            bool mk = ee[q]!=0;
            cnt[q] += mk ? 1 : 0;
            #pragma unroll
            for (int k=0;k<4;++k){
                S[q][k] += mk ? uu[k] : 0.0f;
                M[q][k]  = mk ? fmaxf(M[q][k],uu[k]) : M[q][k];
            }
        }
    }
    __shared__ float rS[64][16][4];
    __shared__ float rM[64][16][4];
    __shared__ int   rC[64][16];
    #pragma unroll
    for (int q=0;q<4;++q){
        int c = jq*4+q;
        #pragma unroll
        for (int k=0;k<4;++k){ rS[sl][c][k]=S[q][k]; rM[sl][c][k]=M[q][k]; }
        rC[sl][c]=cnt[q];
    }
    __syncthreads();
    float aS[4], aM[4]; int aC=0; int c2=0, hf=0;
    if (t < 128){
        c2 = t & 15; hf = t >> 4;
        #pragma unroll
        for(int k=0;k<4;++k){ aS[k]=0.f; aM[k]=-3.4e38f; }
        for (int s2=hf*8; s2<hf*8+8; ++s2){
            aC += rC[s2][c2];
            #pragma unroll
            for(int k=0;k<4;++k){ aS[k]+=rS[s2][c2][k]; aM[k]=fmaxf(aM[k],rM[s2][c2][k]); }
        }
    }
    __syncthreads();
    if (t < 128){
        rC[hf][c2]=aC;
        #pragma unroll
        for(int k=0;k<4;++k){ rS[hf][c2][k]=aS[k]; rM[hf][c2][k]=aM[k]; }
    }
    __syncthreads();
    if (t < 16){
        int cc=0; float Sa[4]={0,0,0,0};
        float Ma[4]={-3.4e38f,-3.4e38f,-3.4e38f,-3.4e38f};
        for (int s2=0;s2<8;++s2){
            cc += rC[s2][t];
            #pragma unroll
            for(int k=0;k<4;++k){ Sa[k]+=rS[s2][t][k]; Ma[k]=fmaxf(Ma[k],rM[s2][t][k]); }
        }
        size_t cj = (size_t)b*1024 + j0 + t;
        float4 v4 = *reinterpret_cast<const float4*>(v_ws + cj*4);
        float vv[4]={v4.x,v4.y,v4.z,v4.w};
        float cf = (float)cc, e1 = cf + 1.0f;
        float gd[4], ge[4];
        #pragma unroll
        for(int k=0;k<4;++k){
            float dk = (Sa[k] + cf*vv[k]) / e1;
            float ek;
            if (cc == 0) ek = 0.0f;
            else { float m1 = Ma[k]+vv[k]; ek = (cc < 1024) ? fmaxf(m1, 0.0f) : m1; }
            gd[k]=gelu_f(dk); ge[k]=gelu_f(ek);
        }
        #pragma unroll
        for(int kk=0;kk<8;++kk){
            float a = b_ffn[kk];
            #pragma unroll
            for(int k=0;k<4;++k)
                a += gd[k]*W_ffn[(4+k)*8+kk] + ge[k]*W_ffn[(8+k)*8+kk];
            Gd_ws[cj*8+kk]=a;
        }
        cnt_ws[cj]=cf;
    }
}

// ---- kernel 3: logits -> w=exp(logit) in LDS; packed-FMA PV; pipelined ----
// Block = (b, jtile of 8 cols, sp i-part). 256 threads, grid 4*128*SPLIT.
// Logit role: (il_w=t>>3 in 0..31, jl_w=t&7) -> writes w (exp applied ONCE).
// PV role:    (jh=t&1, h=(t>>1)&3, dq=(t>>3)&7, ig=t>>6): 4 cols x 8 dims,
//             rows ig*16..+16 per chunk. acc v2f[4][4]; pairwise ig-merge.
// Pipeline: next chunk's edges(2 int)+sU(1 float) prefetched into regs during
// the logit phase; sU published at loop top. 2 barriers/chunk.
template<int SPLIT>
__global__ __launch_bounds__(256) void k_main(
    const float* __restrict__ prev, const int* __restrict__ edges,
    const float* __restrict__ u_ws, const float* __restrict__ v_ws,
    const float* __restrict__ Gd_ws,
    const float* __restrict__ W_ffn, const float* __restrict__ W_fcc,
    const float* __restrict__ b_fcc,
    float* __restrict__ Pws, float* __restrict__ Sws, float* __restrict__ Tws)
{
    int bid = blockIdx.x;
    int sp  = bid & (SPLIT-1);
    int jt  = (bid / SPLIT) & 127;
    int b   = bid / (SPLIT*128);
    int j0  = jt*8;
    int t   = threadIdx.x;
    int jl_w = t & 7, il_w = t >> 3;
    int jh = t & 1, h = (t >> 1) & 3, dq = (t >> 3) & 7, ig = t >> 6;

    __shared__ __align__(16) float sBuf[4736]; // sLog 64*36=2304 / merge 2*64*37
    __shared__ float sU[64][4];
    __shared__ float sV[8][4];
    __shared__ float sGd[8][8];
    float* sLog = sBuf;

    if (t < 32) (&sV[0][0])[t]  = v_ws[((size_t)b*1024 + j0)*4 + t];
    if (t < 64) (&sGd[0][0])[t] = Gd_ws[((size_t)b*1024 + j0)*8 + t];

    // uniform weights -> scalar regs
    float W4r[4][8], Wfc[8][4], bfc[4];
    #pragma unroll
    for(int k=0;k<4;++k)
        #pragma unroll
        for(int kk=0;kk<8;++kk) W4r[k][kk]=W_ffn[k*8+kk];
    #pragma unroll
    for(int kk=0;kk<8;++kk)
        #pragma unroll
        for(int hh=0;hh<4;++hh) Wfc[kk][hh]=W_fcc[kk*4+hh];
    #pragma unroll
    for(int hh=0;hh<4;++hh) bfc[hh]=b_fcc[hh];

    v2f sA = {0,0}, sB = {0,0};                 // sums for cols (0,1),(2,3)
    v2f acc2[4][4];
    #pragma unroll
    for (int c=0;c<4;++c)
        #pragma unroll
        for (int e=0;e<4;++e) acc2[c][e] = (v2f){0.f,0.f};
    float Tp[4] = {0,0,0,0};

    const int*   ebase  = edges + (size_t)b*1048576 + j0;
    const float* pbBase = prev  + (size_t)b*262144 + h*64 + dq*8;

    const int NCH = 16/SPLIT;
    const int base_i0 = sp*(1024/SPLIT);

    // ---- prologue prefetch for chunk 0 ----
    float su_r = u_ws[((size_t)b*1024 + base_i0)*4 + t];
    int   egr0 = ebase[(size_t)(base_i0+il_w   )*1024 + jl_w];
    int   egr1 = ebase[(size_t)(base_i0+il_w+32)*1024 + jl_w];

    for (int cc=0; cc<NCH; ++cc){
        int i0 = base_i0 + cc*64;
        (&sU[0][0])[t] = su_r;                   // publish prefetched sU
        __syncthreads();                         // sU visible; sLog consumed

        // ---- logit phase: 512 pairs, 2 per thread; store w = exp(logit) ----
        int eg2[2] = {egr0, egr1};
        #pragma unroll
        for (int r=0;r<2;++r){
            int il = il_w + 32*r;
            int eg = eg2[r];
            float gc[4];
            #pragma unroll
            for(int k=0;k<4;++k){
                float ccv = sU[il][k] + sV[jl_w][k];
                gc[k] = gelu_f(ccv);
                Tp[k] += eg ? gc[k] : 0.0f;
            }
            float fu[8];
            #pragma unroll
            for(int kk=0;kk<8;++kk){
                float a = sGd[jl_w][kk];
                #pragma unroll
                for(int k=0;k<4;++k) a += gc[k]*W4r[k][kk];
                fu[kk] = gelu_f(a);
            }
            #pragma unroll
            for(int hh=0;hh<4;++hh){
                float a = bfc[hh];
                #pragma unroll
                for(int kk=0;kk<8;++kk) a += fu[kk]*Wfc[kk][hh];
                sLog[il*36 + hh*8 + jl_w] = eg ? __expf(a) : 0.0f;
            }
        }

        // ---- prefetch next chunk (latency hidden under barrier + PV) ----
        {
            int i0n = base_i0 + ((cc+1 < NCH) ? (cc+1)*64 : 0);
            su_r = u_ws[((size_t)b*1024 + i0n)*4 + t];
            egr0 = ebase[(size_t)(i0n+il_w   )*1024 + jl_w];
            egr1 = ebase[(size_t)(i0n+il_w+32)*1024 + jl_w];
        }
        __syncthreads();                         // sLog ready

        // ---- PV (packed fp32): rows ig*16..+16, cols jh*4..+4, 8 dims ----
        const float* pc = pbBase + (size_t)(i0 + ig*16)*256;
        const float* lg = sLog + (ig*16)*36 + h*8 + jh*4;
        #pragma unroll 4
        for (int i=0;i<16;++i){
            float4 lv = *reinterpret_cast<const float4*>(lg + i*36);
            float4 a0 = *reinterpret_cast<const float4*>(pc + (size_t)i*256);
            float4 a1 = *reinterpret_cast<const float4*>(pc + (size_t)i*256 + 4);
            sA += (v2f){lv.x, lv.y};
            sB += (v2f){lv.z, lv.w};
            v2f p01 = {a0.x,a0.y}, p23 = {a0.z,a0.w};
            v2f p45 = {a1.x,a1.y}, p67 = {a1.z,a1.w};
            v2f w0 = {lv.x,lv.x}, w1 = {lv.y,lv.y};
            v2f w2 = {lv.z,lv.z}, w3 = {lv.w,lv.w};
            acc2[0][0]=pk_fma(w0,p01,acc2[0][0]); acc2[0][1]=pk_fma(w0,p23,acc2[0][1]);
            acc2[0][2]=pk_fma(w0,p45,acc2[0][2]); acc2[0][3]=pk_fma(w0,p67,acc2[0][3]);
            acc2[1][0]=pk_fma(w1,p01,acc2[1][0]); acc2[1][1]=pk_fma(w1,p23,acc2[1][1]);
            acc2[1][2]=pk_fma(w1,p45,acc2[1][2]); acc2[1][3]=pk_fma(w1,p67,acc2[1][3]);
            acc2[2][0]=pk_fma(w2,p01,acc2[2][0]); acc2[2][1]=pk_fma(w2,p23,acc2[2][1]);
            acc2[2][2]=pk_fma(w2,p45,acc2[2][2]); acc2[2][3]=pk_fma(w2,p67,acc2[2][3]);
            acc2[3][0]=pk_fma(w3,p01,acc2[3][0]); acc2[3][1]=pk_fma(w3,p23,acc2[3][1]);
            acc2[3][2]=pk_fma(w3,p45,acc2[3][2]); acc2[3][3]=pk_fma(w3,p67,acc2[3][3]);
        }
    }

    float s4[4] = {sA[0], sA[1], sB[0], sB[1]};

    // ---- pairwise ig-merge (plain sums), buffer 2*64*37 floats ----
    int r64 = t & 63;
    __syncthreads();
    if (ig >= 2){
        float* dst = sBuf + (size_t)((ig-2)*64 + r64)*37;
        #pragma unroll
        for (int c=0;c<4;++c) dst[c] = s4[c];
        #pragma unroll
        for (int c=0;c<4;++c)
            #pragma unroll
            for (int e=0;e<4;++e){
                dst[4 + c*8 + 2*e    ] = acc2[c][e][0];
                dst[4 + c*8 + 2*e + 1] = acc2[c][e][1];
            }
    }
    __syncthreads();
    if (ig < 2){
        const float* src = sBuf + (size_t)(ig*64 + r64)*37;
        #pragma unroll
        for (int c=0;c<4;++c) s4[c] += src[c];
        #pragma unroll
        for (int c=0;c<4;++c)
            #pragma unroll
            for (int e=0;e<4;++e){
                acc2[c][e][0] += src[4 + c*8 + 2*e    ];
                acc2[c][e][1] += src[4 + c*8 + 2*e + 1];
            }
    }
    __syncthreads();
    if (ig == 1){
        float* dst = sBuf + (size_t)r64*37;
        #pragma unroll
        for (int c=0;c<4;++c) dst[c] = s4[c];
        #pragma unroll
        for (int c=0;c<4;++c)
            #pragma unroll
            for (int e=0;e<4;++e){
                dst[4 + c*8 + 2*e    ] = acc2[c][e][0];
                dst[4 + c*8 + 2*e + 1] = acc2[c][e][1];
            }
    }
    __syncthreads();
    if (ig == 0){
        const float* src = sBuf + (size_t)t*37;
        #pragma unroll
        for (int c=0;c<4;++c) s4[c] += src[c];
        #pragma unroll
        for (int c=0;c<4;++c)
            #pragma unroll
            for (int e=0;e<4;++e){
                acc2[c][e][0] += src[4 + c*8 + 2*e    ];
                acc2[c][e][1] += src[4 + c*8 + 2*e + 1];
            }
    }

    size_t bp = ((size_t)b*128 + jt)*SPLIT + sp;

    // ---- T reduction (sBuf reused; barrier separates from merge reads) ----
    __syncthreads();
    #pragma unroll
    for (int k=0;k<4;++k) sBuf[(il_w*8 + jl_w)*4 + k] = Tp[k];
    __syncthreads();
    if (t < 8){
        float T0=0,T1=0,T2=0,T3=0;
        for (int s2=0;s2<32;++s2){
            const float* p = sBuf + (s2*8+t)*4;
            T0+=p[0];T1+=p[1];T2+=p[2];T3+=p[3];
        }
        float* td = Tws + (bp*8 + t)*4;
        td[0]=T0; td[1]=T1; td[2]=T2; td[3]=T3;
    }

    // ---- partial outputs from ig==0 threads (t<64) ----
    if (ig == 0){
        if (dq == 0){                       // t = h*2+jh < 8
            #pragma unroll
            for (int c=0;c<4;++c)
                Sws[bp*32 + h*8 + jh*4 + c] = s4[c];
        }
        #pragma unroll
        for (int c=0;c<4;++c){
            float* dst = Pws + (((size_t)bp*8 + jh*4 + c)*32 + h*8 + dq)*8;
            float4* d4 = reinterpret_cast<float4*>(dst);
            d4[0] = make_float4(acc2[c][0][0],acc2[c][0][1],acc2[c][1][0],acc2[c][1][1]);
            d4[1] = make_float4(acc2[c][2][0],acc2[c][2][1],acc2[c][3][0],acc2[c][3][1]);
        }
    }
}

// ---- kernel 4: merge split partials, normalize, add gelu(g)@W_fcg ----
// Block = (b, jtile of 8 cols), grid 512. Thread: jl=t>>5, hd=t&31
// (h=hd>>3, dq=hd&7) -> Pws read is linear in t (coalesced).
template<int SPLIT>
__global__ __launch_bounds__(256) void k_merge(
    const float* __restrict__ Pws, const float* __restrict__ Sws,
    const float* __restrict__ Tws,
    const float* __restrict__ Gd_ws, const float* __restrict__ cnt_ws,
    const float* __restrict__ W_ffn, const float* __restrict__ W_fcg,
    const float* __restrict__ b_fcg, float* __restrict__ out)
{
    int b  = blockIdx.x >> 7;
    int jt = blockIdx.x & 127;
    int j0 = jt*8;
    int t  = threadIdx.x;
    int jl = t >> 5, hd = t & 31, h = hd >> 3, dq = hd & 7;
    __shared__ float sG[8][8];

    size_t bp0 = ((size_t)b*128 + jt)*SPLIT;
    float s = 0.0f, acc[8] = {0,0,0,0,0,0,0,0};
    #pragma unroll
    for (int sp2=0; sp2<SPLIT; ++sp2){
        const float* p = Pws + ((bp0+sp2)*256 + t)*8;
        float4 p0 = *reinterpret_cast<const float4*>(p);
        float4 p1 = *reinterpret_cast<const float4*>(p+4);
        acc[0]+=p0.x; acc[1]+=p0.y; acc[2]+=p0.z; acc[3]+=p0.w;
        acc[4]+=p1.x; acc[5]+=p1.y; acc[6]+=p1.z; acc[7]+=p1.w;
        s += Sws[(bp0+sp2)*32 + h*8 + jl];
    }
    if (t < 8){
        float T[4] = {0,0,0,0};
        #pragma unroll
        for (int sp2=0; sp2<SPLIT; ++sp2){
            const float* tp = Tws + ((bp0+sp2)*8 + t)*4;
            #pragma unroll
            for (int k=0;k<4;++k) T[k]+=tp[k];
        }
        size_t cj = (size_t)b*1024 + j0 + t;
        float cf = cnt_ws[cj];
        float inv = __fdividef(1.0f, cf + 1.0f);
        #pragma unroll
        for (int kk=0;kk<8;++kk){
            float a = cf*Gd_ws[cj*8+kk];
            #pragma unroll
            for (int k=0;k<4;++k) a += T[k]*W_ffn[k*8+kk];
            sG[t][kk] = gelu_f(a*inv);
        }
    }
    __syncthreads();

    float rs = (s > 0.0f) ? (1.0f/s) : 0.0f;
    int col0 = h*64 + dq*8;
    float gg[8];
    #pragma unroll
    for (int kk=0;kk<8;++kk) gg[kk]=sG[jl][kk];
    float o[8];
    #pragma unroll
    for (int d2=0;d2<8;++d2){
        float a = b_fcg[col0+d2];
        #pragma unroll
        for (int kk=0;kk<8;++kk) a += gg[kk]*W_fcg[kk*256 + col0 + d2];
        o[d2] = acc[d2]*rs + a;
    }
    float* ob = out + ((size_t)b*1024 + j0 + jl)*256 + col0;
    float4* o4 = reinterpret_cast<float4*>(ob);
    o4[0] = make_float4(o[0],o[1],o[2],o[3]);
    o4[1] = make_float4(o[4],o[5],o[6],o[7]);
}

extern "C" void kernel_launch(void* const* d_in, const int* in_sizes, int n_in,
                              void* d_out, int out_size, void* d_ws, size_t ws_size,
                              hipStream_t stream)
{
    const float* prev  = (const float*)d_in[0];
    const float* curr  = (const float*)d_in[1];
    const int*   edges = (const int*)  d_in[2];
    const float* W_pre = (const float*)d_in[3];
    const float* b_pre = (const float*)d_in[4];
    const float* W_cur = (const float*)d_in[5];
    const float* b_cur = (const float*)d_in[6];
    const float* W_fuse= (const float*)d_in[7];
    const float* b_fuse= (const float*)d_in[8];
    const float* W_ffn = (const float*)d_in[9];
    const float* b_ffn = (const float*)d_in[10];
    const float* W_fcc = (const float*)d_in[11];
    const float* b_fcc = (const float*)d_in[12];
    const float* W_fcg = (const float*)d_in[13];
    const float* b_fcg = (const float*)d_in[14];
    float* out = (float*)d_out;

    float* u_ws   = (float*)d_ws;          // 16384 floats
    float* v_ws   = u_ws  + 16384;         // 16384
    float* Gd_ws  = v_ws  + 16384;         // 32768
    float* cnt_ws = Gd_ws + 32768;         // 4096
    float* Pws    = cnt_ws + 4096;
    const size_t base_f = 16384 + 16384 + 32768 + 4096;

    k_rows<<<dim3(2048), dim3(256), 0, stream>>>(prev, curr, W_pre, b_pre,
        W_cur, b_cur, W_fuse, b_fuse, u_ws, v_ws);
    k_cols<<<dim3(256), dim3(256), 0, stream>>>(edges, u_ws, v_ws,
        W_ffn, b_ffn, Gd_ws, cnt_ws);

    const size_t p4 = (size_t)4*128*4*256*8, s4 = (size_t)4*128*4*32,
                 t4 = (size_t)4*128*4*8*4;
    const size_t p2 = p4/2, s2v = s4/2, t2 = t4/2;
    const size_t need4 = (base_f + p4 + s4 + t4) * 4;
    const size_t need2 = (base_f + p2 + s2v + t2) * 4;

    if (ws_size >= need4){
        float* Sws = Pws + p4;
        float* Tws = Sws + s4;
        k_main<4><<<dim3(2048), dim3(256), 0, stream>>>(prev, edges, u_ws, v_ws,
            Gd_ws, W_ffn, W_fcc, b_fcc, Pws, Sws, Tws);
        k_merge<4><<<dim3(512), dim3(256), 0, stream>>>(Pws, Sws, Tws, Gd_ws,
            cnt_ws, W_ffn, W_fcg, b_fcg, out);
    } else if (ws_size >= need2){
        float* Sws = Pws + p2;
        float* Tws = Sws + s2v;
        k_main<2><<<dim3(1024), dim3(256), 0, stream>>>(prev, edges, u_ws, v_ws,
            Gd_ws, W_ffn, W_fcc, b_fcc, Pws, Sws, Tws);
        k_merge<2><<<dim3(512), dim3(256), 0, stream>>>(Pws, Sws, Tws, Gd_ws,
            cnt_ws, W_ffn, W_fcg, b_fcg, out);
    } else {
        const size_t p1 = p4/4, s1 = s4/4;
        float* Sws = Pws + p1;
        float* Tws = Sws + s1;
        k_main<1><<<dim3(512), dim3(256), 0, stream>>>(prev, edges, u_ws, v_ws,
            Gd_ws, W_ffn, W_fcc, b_fcc, Pws, Sws, Tws);
        k_merge<1><<<dim3(512), dim3(256), 0, stream>>>(Pws, Sws, Tws, Gd_ws,
            cnt_ws, W_ffn, W_fcg, b_fcg, out);
    }
}

// Round 12
// 110.104 us; speedup vs baseline: 1.4819x; 1.0219x over previous
//
#include <hip/hip_runtime.h>

// ---------------------------------------------------------------------------
// B=4, N1=1024, N2=1024, D=256, H=4, Dh=64
//   u[b,i,4] = gelu(prev@W_pre+b_pre) @ W_fuse[0:6]
//   v[b,j,4] = gelu(curr@W_cur+b_cur) @ W_fuse[6:12] + b_fuse
//   c = mask ? u_i+v_j : 0
//   Gd_j[8] = gelu(d_j)@W_ffn[4:8] + gelu(e_j)@W_ffn[8:12] + b_ffn
//   logits = gelu(gelu(c)@W_ffn[0:4] + Gd_j)@W_fcc + b_fcc
//   softmax over i WITHOUT max-subtraction (masked -> w=0); plain-sum partials
//   res = P @ prev (per-head);  g_j = (T_j@W_ffn[0:4]+cnt*Gd_j)/(cnt+1)
//   out = res + gelu(g)@W_fcg + b_fcg
// Round-11 lesson: PV VALU was not the wall (pk_fma gave +2.5us); the logit
//   chain is. Edges are ~50% dense: two-pass logit with cross-wave ballot
//   compaction runs the fu/logit/exp chain only for ACTIVE pairs; pass 1
//   computes gc for all (T needs it; fixed jl per thread keeps Tp valid)
//   and caches it in LDS.
// Round-9 lesson: exp once at sLog-write (not 8x in PV).
// Round-7 lesson: 1 col/thread -> 8x VMEM, latency-bound. acc 4colsx8dims.
// Round-6 lesson: softmax denominators are PER (column, HEAD).
// Round-5 lesson: >128 VGPR cliff. Round-4: never cap min-waves (spill).
// ---------------------------------------------------------------------------

typedef float v2f __attribute__((ext_vector_type(2)));
__device__ __forceinline__ v2f pk_fma(v2f a, v2f b, v2f c){
    return __builtin_elementwise_fma(a, b, c);
}

__device__ __forceinline__ float gelu_f(float x){
    float x2 = x*x;
    float tt = x * __builtin_fmaf(0.044715f, x2, 1.0f);   // x + 0.044715 x^3
    float e  = exp2f(2.3022082f * tt);                    // exp(1.59576912*tt)
    return x - __fdividef(x, e + 1.0f);
}

// ---- kernel 1: per-row u (prev side) and v (curr side), one wave per row ----
__global__ __launch_bounds__(256) void k_rows(
    const float* __restrict__ prev, const float* __restrict__ curr,
    const float* __restrict__ W_pre, const float* __restrict__ b_pre,
    const float* __restrict__ W_cur, const float* __restrict__ b_cur,
    const float* __restrict__ W_fuse, const float* __restrict__ b_fuse,
    float* __restrict__ u_ws, float* __restrict__ v_ws)
{
    int gid  = blockIdx.x * 256 + threadIdx.x;
    int wave = gid >> 6;
    int lane = threadIdx.x & 63;
    bool isPrev = wave < 4096;
    int row = isPrev ? wave : (wave - 4096);
    const float* xrow = (isPrev ? prev : curr) + (size_t)row * 256;
    const float* W  = isPrev ? W_pre : W_cur;
    const float* bv = isPrev ? b_pre : b_cur;

    float4 x4 = *reinterpret_cast<const float4*>(xrow + lane*4);
    const float* Wl = W + lane*24;
    float p[6];
    #pragma unroll
    for (int k=0;k<6;++k)
        p[k] = x4.x*Wl[k] + x4.y*Wl[6+k] + x4.z*Wl[12+k] + x4.w*Wl[18+k];
    #pragma unroll
    for (int off=32; off>=1; off>>=1){
        #pragma unroll
        for (int k=0;k<6;++k) p[k] += __shfl_xor(p[k], off, 64);
    }
    if (lane == 0){
        float g[6];
        #pragma unroll
        for(int k=0;k<6;++k) g[k] = gelu_f(p[k] + bv[k]);
        int rb = isPrev ? 0 : 6;
        float o[4];
        #pragma unroll
        for(int kk=0;kk<4;++kk){
            float a = isPrev ? 0.0f : b_fuse[kk];
            #pragma unroll
            for(int k=0;k<6;++k) a += g[k]*W_fuse[(rb+k)*4+kk];
            o[kk]=a;
        }
        float* dst = (isPrev ? u_ws : v_ws) + (size_t)row*4;
        *reinterpret_cast<float4*>(dst) = make_float4(o[0],o[1],o[2],o[3]);
    }
}

// ---- kernel 2: per-column reductions over edges + Gd precompute ----
__global__ __launch_bounds__(256) void k_cols(
    const int* __restrict__ edges,
    const float* __restrict__ u_ws, const float* __restrict__ v_ws,
    const float* __restrict__ W_ffn, const float* __restrict__ b_ffn,
    float* __restrict__ Gd_ws, float* __restrict__ cnt_ws)
{
    int b  = blockIdx.x >> 6;
    int j0 = (blockIdx.x & 63) * 16;
    int t  = threadIdx.x;
    int jq = t & 3, sl = t >> 2;
    const int*   eb = edges + (size_t)b*1048576 + j0 + jq*4;
    const float* ub = u_ws + (size_t)b*4096;

    int   cnt[4] = {0,0,0,0};
    float S[4][4] = {{0.f}};
    float M[4][4];
    #pragma unroll
    for (int q=0;q<4;++q)
        #pragma unroll
        for (int k=0;k<4;++k) M[q][k] = -3.4e38f;

    #pragma unroll 4
    for (int ii=0; ii<16; ++ii){
        int i = sl*16 + ii;
        int4   e4 = *reinterpret_cast<const int4*>(eb + (size_t)i*1024);
        float4 u4 = *reinterpret_cast<const float4*>(ub + i*4);
        float uu[4] = {u4.x,u4.y,u4.z,u4.w};
        int   ee[4] = {e4.x,e4.y,e4.z,e4.w};
        #pragma unroll
        for (int q=0;q<4;++q){
            bool mk = ee[q]!=0;
            cnt[q] += mk ? 1 : 0;
            #pragma unroll
            for (int k=0;k<4;++k){
                S[q][k] += mk ? uu[k] : 0.0f;
                M[q][k]  = mk ? fmaxf(M[q][k],uu[k]) : M[q][k];
            }
        }
    }
    __shared__ float rS[64][16][4];
    __shared__ float rM[64][16][4];
    __shared__ int   rC[64][16];
    #pragma unroll
    for (int q=0;q<4;++q){
        int c = jq*4+q;
        #pragma unroll
        for (int k=0;k<4;++k){ rS[sl][c][k]=S[q][k]; rM[sl][c][k]=M[q][k]; }
        rC[sl][c]=cnt[q];
    }
    __syncthreads();
    float aS[4], aM[4]; int aC=0; int c2=0, hf=0;
    if (t < 128){
        c2 = t & 15; hf = t >> 4;
        #pragma unroll
        for(int k=0;k<4;++k){ aS[k]=0.f; aM[k]=-3.4e38f; }
        for (int s2=hf*8; s2<hf*8+8; ++s2){
            aC += rC[s2][c2];
            #pragma unroll
            for(int k=0;k<4;++k){ aS[k]+=rS[s2][c2][k]; aM[k]=fmaxf(aM[k],rM[s2][c2][k]); }
        }
    }
    __syncthreads();
    if (t < 128){
        rC[hf][c2]=aC;
        #pragma unroll
        for(int k=0;k<4;++k){ rS[hf][c2][k]=aS[k]; rM[hf][c2][k]=aM[k]; }
    }
    __syncthreads();
    if (t < 16){
        int cc=0; float Sa[4]={0,0,0,0};
        float Ma[4]={-3.4e38f,-3.4e38f,-3.4e38f,-3.4e38f};
        for (int s2=0;s2<8;++s2){
            cc += rC[s2][t];
            #pragma unroll
            for(int k=0;k<4;++k){ Sa[k]+=rS[s2][t][k]; Ma[k]=fmaxf(Ma[k],rM[s2][t][k]); }
        }
        size_t cj = (size_t)b*1024 + j0 + t;
        float4 v4 = *reinterpret_cast<const float4*>(v_ws + cj*4);
        float vv[4]={v4.x,v4.y,v4.z,v4.w};
        float cf = (float)cc, e1 = cf + 1.0f;
        float gd[4], ge[4];
        #pragma unroll
        for(int k=0;k<4;++k){
            float dk = (Sa[k] + cf*vv[k]) / e1;
            float ek;
            if (cc == 0) ek = 0.0f;
            else { float m1 = Ma[k]+vv[k]; ek = (cc < 1024) ? fmaxf(m1, 0.0f) : m1; }
            gd[k]=gelu_f(dk); ge[k]=gelu_f(ek);
        }
        #pragma unroll
        for(int kk=0;kk<8;++kk){
            float a = b_ffn[kk];
            #pragma unroll
            for(int k=0;k<4;++k)
                a += gd[k]*W_ffn[(4+k)*8+kk] + ge[k]*W_ffn[(8+k)*8+kk];
            Gd_ws[cj*8+kk]=a;
        }
        cnt_ws[cj]=cf;
    }
}

// ---- kernel 3: two-pass compacted logits + packed-FMA PV ----
// Block = (b, jtile of 8 cols, sp i-part). 256 threads, grid 4*128*SPLIT.
// Pass1 (all 512 pairs, fixed (il_w,jl_w)/thread): gc gelus -> Tp + sGc cache,
//   zero sLog slots. Ballot-compacted list of active pairs -> sPairs.
// Pass2 (~50% pairs): fu chain + logits + exp, one active pair per thread.
// PV role: (jh=t&1, h=(t>>1)&3, dq=(t>>3)&7, ig=t>>6): 4 cols x 8 dims.
template<int SPLIT>
__global__ __launch_bounds__(256) void k_main(
    const float* __restrict__ prev, const int* __restrict__ edges,
    const float* __restrict__ u_ws, const float* __restrict__ v_ws,
    const float* __restrict__ Gd_ws,
    const float* __restrict__ W_ffn, const float* __restrict__ W_fcc,
    const float* __restrict__ b_fcc,
    float* __restrict__ Pws, float* __restrict__ Sws, float* __restrict__ Tws)
{
    int bid = blockIdx.x;
    int sp  = bid & (SPLIT-1);
    int jt  = (bid / SPLIT) & 127;
    int b   = bid / (SPLIT*128);
    int j0  = jt*8;
    int t   = threadIdx.x;
    int lane = t & 63;
    int wv   = t >> 6;
    int jl_w = t & 7, il_w = t >> 3;
    int jh = t & 1, h = (t >> 1) & 3, dq = (t >> 3) & 7, ig = t >> 6;

    __shared__ __align__(16) float sBuf[2368];  // sLog 64*36 / merge 64*37 / sT
    __shared__ __align__(16) float sU[64][4];
    __shared__ __align__(16) float sV[8][4];
    __shared__ __align__(16) float sGd[8][8];
    __shared__ __align__(16) float sGc[512][4]; // gc cache, indexed by pair id
    __shared__ unsigned short sPairs[512];
    __shared__ unsigned long long sBal[8];
    float* sLog = sBuf;

    if (t < 32) (&sV[0][0])[t]  = v_ws[((size_t)b*1024 + j0)*4 + t];
    if (t < 64) (&sGd[0][0])[t] = Gd_ws[((size_t)b*1024 + j0)*8 + t];

    // uniform weights -> scalar regs
    float W4r[4][8], Wfc[8][4], bfc[4];
    #pragma unroll
    for(int k=0;k<4;++k)
        #pragma unroll
        for(int kk=0;kk<8;++kk) W4r[k][kk]=W_ffn[k*8+kk];
    #pragma unroll
    for(int kk=0;kk<8;++kk)
        #pragma unroll
        for(int hh=0;hh<4;++hh) Wfc[kk][hh]=W_fcc[kk*4+hh];
    #pragma unroll
    for(int hh=0;hh<4;++hh) bfc[hh]=b_fcc[hh];

    v2f sA = {0,0}, sB = {0,0};
    v2f acc2[4][4];
    #pragma unroll
    for (int c=0;c<4;++c)
        #pragma unroll
        for (int e=0;e<4;++e) acc2[c][e] = (v2f){0.f,0.f};
    float Tp[4] = {0,0,0,0};

    const int*   ebase  = edges + (size_t)b*1048576 + j0;
    const float* pbBase = prev  + (size_t)b*262144 + h*64 + dq*8;

    const int NCH = 16/SPLIT;
    const int base_i0 = sp*(1024/SPLIT);

    __syncthreads();                              // sV/sGd visible
    float4 v4p = *reinterpret_cast<const float4*>(&sV[jl_w][0]);

    // ---- prologue prefetch for chunk 0 ----
    float su_r = u_ws[((size_t)b*1024 + base_i0)*4 + t];
    int   egr0 = ebase[(size_t)(base_i0+il_w   )*1024 + jl_w];
    int   egr1 = ebase[(size_t)(base_i0+il_w+32)*1024 + jl_w];

    for (int cc=0; cc<NCH; ++cc){
        int i0 = base_i0 + cc*64;
        (&sU[0][0])[t] = su_r;                    // publish prefetched sU
        __syncthreads();                          // B1: sU visible, PV done

        // ---- pass 1: gc for all pairs -> Tp + sGc; zero sLog slots ----
        int eg2[2] = {egr0, egr1};
        #pragma unroll
        for (int r=0;r<2;++r){
            int il = il_w + 32*r;
            int eg = eg2[r];
            float4 u4 = *reinterpret_cast<const float4*>(&sU[il][0]);
            float g0 = gelu_f(u4.x + v4p.x);
            float g1 = gelu_f(u4.y + v4p.y);
            float g2 = gelu_f(u4.z + v4p.z);
            float g3 = gelu_f(u4.w + v4p.w);
            Tp[0] += eg ? g0 : 0.0f;
            Tp[1] += eg ? g1 : 0.0f;
            Tp[2] += eg ? g2 : 0.0f;
            Tp[3] += eg ? g3 : 0.0f;
            int pid = il*8 + jl_w;
            *reinterpret_cast<float4*>(&sGc[pid][0]) = make_float4(g0,g1,g2,g3);
            sLog[il*36 +  0 + jl_w] = 0.0f;
            sLog[il*36 +  8 + jl_w] = 0.0f;
            sLog[il*36 + 16 + jl_w] = 0.0f;
            sLog[il*36 + 24 + jl_w] = 0.0f;
        }
        // ---- ballots -> compaction list ----
        unsigned long long b0 = __ballot(egr0 != 0);
        unsigned long long b1 = __ballot(egr1 != 0);
        if (lane == 0){ sBal[wv*2] = b0; sBal[wv*2+1] = b1; }
        __syncthreads();                          // B2: sBal + zeros + sGc ready
        int base = 0, total = 0;
        #pragma unroll
        for (int w2 = 0; w2 < 4; ++w2){
            int c = __popcll(sBal[2*w2]) + __popcll(sBal[2*w2+1]);
            if (w2 < wv) base += c;
            total += c;
        }
        unsigned long long lm = (1ull << lane) - 1ull;
        int p0 = base + (int)__popcll(b0 & lm);
        int p1 = base + (int)__popcll(b0) + (int)__popcll(b1 & lm);
        if (egr0) sPairs[p0] = (unsigned short)(il_w*8 + jl_w);
        if (egr1) sPairs[p1] = (unsigned short)((il_w+32)*8 + jl_w);

        // ---- prefetch next chunk (after egr consumed) ----
        {
            int i0n = base_i0 + ((cc+1 < NCH) ? (cc+1)*64 : 0);
            su_r = u_ws[((size_t)b*1024 + i0n)*4 + t];
            egr0 = ebase[(size_t)(i0n+il_w   )*1024 + jl_w];
            egr1 = ebase[(size_t)(i0n+il_w+32)*1024 + jl_w];
        }
        __syncthreads();                          // B3: sPairs ready

        // ---- pass 2: fu chain + logits + exp, active pairs only ----
        for (int p = t; p < total; p += 256){
            int pid = sPairs[p];
            int il = pid >> 3, jl = pid & 7;
            float4 gcv = *reinterpret_cast<const float4*>(&sGc[pid][0]);
            float4 gd0 = *reinterpret_cast<const float4*>(&sGd[jl][0]);
            float4 gd1 = *reinterpret_cast<const float4*>(&sGd[jl][4]);
            float gdv[8] = {gd0.x,gd0.y,gd0.z,gd0.w,gd1.x,gd1.y,gd1.z,gd1.w};
            float fu[8];
            #pragma unroll
            for (int kk=0;kk<8;++kk){
                float a = gdv[kk];
                a = __builtin_fmaf(gcv.x, W4r[0][kk], a);
                a = __builtin_fmaf(gcv.y, W4r[1][kk], a);
                a = __builtin_fmaf(gcv.z, W4r[2][kk], a);
                a = __builtin_fmaf(gcv.w, W4r[3][kk], a);
                fu[kk] = gelu_f(a);
            }
            #pragma unroll
            for (int hh=0;hh<4;++hh){
                float a = bfc[hh];
                #pragma unroll
                for (int kk=0;kk<8;++kk) a = __builtin_fmaf(fu[kk], Wfc[kk][hh], a);
                sLog[il*36 + hh*8 + jl] = exp2f(a * 1.4426950408889634f);
            }
        }
        __syncthreads();                          // B4: sLog ready

        // ---- PV (packed fp32): rows ig*16..+16, cols jh*4..+4, 8 dims ----
        const float* pc = pbBase + (size_t)(i0 + ig*16)*256;
        const float* lg = sLog + (ig*16)*36 + h*8 + jh*4;
        #pragma unroll 4
        for (int i=0;i<16;++i){
            float4 lv = *reinterpret_cast<const float4*>(lg + i*36);
            float4 a0 = *reinterpret_cast<const float4*>(pc + (size_t)i*256);
            float4 a1 = *reinterpret_cast<const float4*>(pc + (size_t)i*256 + 4);
            sA += (v2f){lv.x, lv.y};
            sB += (v2f){lv.z, lv.w};
            v2f p01 = {a0.x,a0.y}, p23 = {a0.z,a0.w};
            v2f p45 = {a1.x,a1.y}, p67 = {a1.z,a1.w};
            v2f w0 = {lv.x,lv.x}, w1 = {lv.y,lv.y};
            v2f w2 = {lv.z,lv.z}, w3 = {lv.w,lv.w};
            acc2[0][0]=pk_fma(w0,p01,acc2[0][0]); acc2[0][1]=pk_fma(w0,p23,acc2[0][1]);
            acc2[0][2]=pk_fma(w0,p45,acc2[0][2]); acc2[0][3]=pk_fma(w0,p67,acc2[0][3]);
            acc2[1][0]=pk_fma(w1,p01,acc2[1][0]); acc2[1][1]=pk_fma(w1,p23,acc2[1][1]);
            acc2[1][2]=pk_fma(w1,p45,acc2[1][2]); acc2[1][3]=pk_fma(w1,p67,acc2[1][3]);
            acc2[2][0]=pk_fma(w2,p01,acc2[2][0]); acc2[2][1]=pk_fma(w2,p23,acc2[2][1]);
            acc2[2][2]=pk_fma(w2,p45,acc2[2][2]); acc2[2][3]=pk_fma(w2,p67,acc2[2][3]);
            acc2[3][0]=pk_fma(w3,p01,acc2[3][0]); acc2[3][1]=pk_fma(w3,p23,acc2[3][1]);
            acc2[3][2]=pk_fma(w3,p45,acc2[3][2]); acc2[3][3]=pk_fma(w3,p67,acc2[3][3]);
        }
    }

    float s4[4] = {sA[0], sA[1], sB[0], sB[1]};

    // ---- ig-merge, single 64-slot buffer, 3 rounds (plain sums) ----
    int r64 = t & 63;
    #pragma unroll
    for (int g = 3; g >= 1; --g){
        __syncthreads();
        if (ig == g){
            float* dst = sBuf + (size_t)r64*37;
            #pragma unroll
            for (int c=0;c<4;++c) dst[c] = s4[c];
            #pragma unroll
            for (int c=0;c<4;++c)
                #pragma unroll
                for (int e=0;e<4;++e){
                    dst[4 + c*8 + 2*e    ] = acc2[c][e][0];
                    dst[4 + c*8 + 2*e + 1] = acc2[c][e][1];
                }
        }
        __syncthreads();
        if (ig == 0){
            const float* src = sBuf + (size_t)t*37;
            #pragma unroll
            for (int c=0;c<4;++c) s4[c] += src[c];
            #pragma unroll
            for (int c=0;c<4;++c)
                #pragma unroll
                for (int e=0;e<4;++e){
                    acc2[c][e][0] += src[4 + c*8 + 2*e    ];
                    acc2[c][e][1] += src[4 + c*8 + 2*e + 1];
                }
        }
    }

    size_t bp = ((size_t)b*128 + jt)*SPLIT + sp;

    // ---- T reduction (sBuf reused; barrier separates from merge reads) ----
    __syncthreads();
    #pragma unroll
    for (int k=0;k<4;++k) sBuf[(il_w*8 + jl_w)*4 + k] = Tp[k];
    __syncthreads();
    if (t < 8){
        float T0=0,T1=0,T2=0,T3=0;
        for (int s2=0;s2<32;++s2){
            const float* p = sBuf + (s2*8+t)*4;
            T0+=p[0];T1+=p[1];T2+=p[2];T3+=p[3];
        }
        float* td = Tws + (bp*8 + t)*4;
        td[0]=T0; td[1]=T1; td[2]=T2; td[3]=T3;
    }

    // ---- partial outputs from ig==0 threads (t<64) ----
    if (ig == 0){
        if (dq == 0){                       // t = h*2+jh < 8
            #pragma unroll
            for (int c=0;c<4;++c)
                Sws[bp*32 + h*8 + jh*4 + c] = s4[c];
        }
        #pragma unroll
        for (int c=0;c<4;++c){
            float* dst = Pws + (((size_t)bp*8 + jh*4 + c)*32 + h*8 + dq)*8;
            float4* d4 = reinterpret_cast<float4*>(dst);
            d4[0] = make_float4(acc2[c][0][0],acc2[c][0][1],acc2[c][1][0],acc2[c][1][1]);
            d4[1] = make_float4(acc2[c][2][0],acc2[c][2][1],acc2[c][3][0],acc2[c][3][1]);
        }
    }
}

// ---- kernel 4: merge split partials, normalize, add gelu(g)@W_fcg ----
template<int SPLIT>
__global__ __launch_bounds__(256) void k_merge(
    const float* __restrict__ Pws, const float* __restrict__ Sws,
    const float* __restrict__ Tws,
    const float* __restrict__ Gd_ws, const float* __restrict__ cnt_ws,
    const float* __restrict__ W_ffn, const float* __restrict__ W_fcg,
    const float* __restrict__ b_fcg, float* __restrict__ out)
{
    int b  = blockIdx.x >> 7;
    int jt = blockIdx.x & 127;
    int j0 = jt*8;
    int t  = threadIdx.x;
    int jl = t >> 5, hd = t & 31, h = hd >> 3, dq = hd & 7;
    __shared__ float sG[8][8];

    size_t bp0 = ((size_t)b*128 + jt)*SPLIT;
    float s = 0.0f, acc[8] = {0,0,0,0,0,0,0,0};
    #pragma unroll
    for (int sp2=0; sp2<SPLIT; ++sp2){
        const float* p = Pws + ((bp0+sp2)*256 + t)*8;
        float4 p0 = *reinterpret_cast<const float4*>(p);
        float4 p1 = *reinterpret_cast<const float4*>(p+4);
        acc[0]+=p0.x; acc[1]+=p0.y; acc[2]+=p0.z; acc[3]+=p0.w;
        acc[4]+=p1.x; acc[5]+=p1.y; acc[6]+=p1.z; acc[7]+=p1.w;
        s += Sws[(bp0+sp2)*32 + h*8 + jl];
    }
    if (t < 8){
        float T[4] = {0,0,0,0};
        #pragma unroll
        for (int sp2=0; sp2<SPLIT; ++sp2){
            const float* tp = Tws + ((bp0+sp2)*8 + t)*4;
            #pragma unroll
            for (int k=0;k<4;++k) T[k]+=tp[k];
        }
        size_t cj = (size_t)b*1024 + j0 + t;
        float cf = cnt_ws[cj];
        float inv = __fdividef(1.0f, cf + 1.0f);
        #pragma unroll
        for (int kk=0;kk<8;++kk){
            float a = cf*Gd_ws[cj*8+kk];
            #pragma unroll
            for (int k=0;k<4;++k) a += T[k]*W_ffn[k*8+kk];
            sG[t][kk] = gelu_f(a*inv);
        }
    }
    __syncthreads();

    float rs = (s > 0.0f) ? (1.0f/s) : 0.0f;
    int col0 = h*64 + dq*8;
    float gg[8];
    #pragma unroll
    for (int kk=0;kk<8;++kk) gg[kk]=sG[jl][kk];
    float o[8];
    #pragma unroll
    for (int d2=0;d2<8;++d2){
        float a = b_fcg[col0+d2];
        #pragma unroll
        for (int kk=0;kk<8;++kk) a += gg[kk]*W_fcg[kk*256 + col0 + d2];
        o[d2] = acc[d2]*rs + a;
    }
    float* ob = out + ((size_t)b*1024 + j0 + jl)*256 + col0;
    float4* o4 = reinterpret_cast<float4*>(ob);
    o4[0] = make_float4(o[0],o[1],o[2],o[3]);
    o4[1] = make_float4(o[4],o[5],o[6],o[7]);
}

extern "C" void kernel_launch(void* const* d_in, const int* in_sizes, int n_in,
                              void* d_out, int out_size, void* d_ws, size_t ws_size,
                              hipStream_t stream)
{
    const float* prev  = (const float*)d_in[0];
    const float* curr  = (const float*)d_in[1];
    const int*   edges = (const int*)  d_in[2];
    const float* W_pre = (const float*)d_in[3];
    const float* b_pre = (const float*)d_in[4];
    const float* W_cur = (const float*)d_in[5];
    const float* b_cur = (const float*)d_in[6];
    const float* W_fuse= (const float*)d_in[7];
    const float* b_fuse= (const float*)d_in[8];
    const float* W_ffn = (const float*)d_in[9];
    const float* b_ffn = (const float*)d_in[10];
    const float* W_fcc = (const float*)d_in[11];
    const float* b_fcc = (const float*)d_in[12];
    const float* W_fcg = (const float*)d_in[13];
    const float* b_fcg = (const float*)d_in[14];
    float* out = (float*)d_out;

    float* u_ws   = (float*)d_ws;          // 16384 floats
    float* v_ws   = u_ws  + 16384;         // 16384
    float* Gd_ws  = v_ws  + 16384;         // 32768
    float* cnt_ws = Gd_ws + 32768;         // 4096
    float* Pws    = cnt_ws + 4096;
    const size_t base_f = 16384 + 16384 + 32768 + 4096;

    k_rows<<<dim3(2048), dim3(256), 0, stream>>>(prev, curr, W_pre, b_pre,
        W_cur, b_cur, W_fuse, b_fuse, u_ws, v_ws);
    k_cols<<<dim3(256), dim3(256), 0, stream>>>(edges, u_ws, v_ws,
        W_ffn, b_ffn, Gd_ws, cnt_ws);

    const size_t p4 = (size_t)4*128*4*256*8, s4 = (size_t)4*128*4*32,
                 t4 = (size_t)4*128*4*8*4;
    const size_t p2 = p4/2, s2v = s4/2, t2 = t4/2;
    const size_t need4 = (base_f + p4 + s4 + t4) * 4;
    const size_t need2 = (base_f + p2 + s2v + t2) * 4;

    if (ws_size >= need4){
        float* Sws = Pws + p4;
        float* Tws = Sws + s4;
        k_main<4><<<dim3(2048), dim3(256), 0, stream>>>(prev, edges, u_ws, v_ws,
            Gd_ws, W_ffn, W_fcc, b_fcc, Pws, Sws, Tws);
        k_merge<4><<<dim3(512), dim3(256), 0, stream>>>(Pws, Sws, Tws, Gd_ws,
            cnt_ws, W_ffn, W_fcg, b_fcg, out);
    } else if (ws_size >= need2){
        float* Sws = Pws + p2;
        float* Tws = Sws + s2v;
        k_main<2><<<dim3(1024), dim3(256), 0, stream>>>(prev, edges, u_ws, v_ws,
            Gd_ws, W_ffn, W_fcc, b_fcc, Pws, Sws, Tws);
        k_merge<2><<<dim3(512), dim3(256), 0, stream>>>(Pws, Sws, Tws, Gd_ws,
            cnt_ws, W_ffn, W_fcg, b_fcg, out);
    } else {
        const size_t p1 = p4/4, s1 = s4/4;
        float* Sws = Pws + p1;
        float* Tws = Sws + s1;
        k_main<1><<<dim3(512), dim3(256), 0, stream>>>(prev, edges, u_ws, v_ws,
            Gd_ws, W_ffn, W_fcc, b_fcc, Pws, Sws, Tws);
        k_merge<1><<<dim3(512), dim3(256), 0, stream>>>(Pws, Sws, Tws, Gd_ws,
            cnt_ws, W_ffn, W_fcg, b_fcg, out);
    }
}